// Round 13
// baseline (386.932 us; speedup 1.0000x reference)
//
#include <hip/hip_runtime.h>
#include <hip/hip_bf16.h>

#define N_NODES 50000
#define N_EDGES 800000
#define DIM 64
#define NB 391      // dst buckets of 128 nodes: ceil(50000/128)
#define NBLK 128    // blocks in bucketize pass
#define CHUNK 6250  // N_EDGES / NBLK (exact)
#define CAP 4096    // LDS staging capacity per bucket segment (avg ~2048)
#define NTILES 3125 // 50000 / 16 row-tiles (exact)
#define FROWS 32    // fused kernel: rows (nodes) per block
#define FPAD 68     // LDS row stride (floats): 16B-aligned, 68%32=4 -> 2-way banks

typedef __attribute__((ext_vector_type(8))) short bf16x8;
typedef __attribute__((ext_vector_type(4))) float f32x4;

// ---------- helpers ----------
__device__ __forceinline__ float bf2f(unsigned short u) {
  return __uint_as_float(((unsigned int)u) << 16);
}
__device__ __forceinline__ unsigned short f2bf(float f) {
  unsigned int x = __float_as_uint(f);
  unsigned int r = (x + 0x7fffu + ((x >> 16) & 1u)) >> 16;  // RNE
  return (unsigned short)r;
}

// ---------- dtype detection (flags[0]=bf16 inputs, flags[1]=int64 indices) ----------
__global__ void k_detect(const unsigned short* __restrict__ feat,
                         const unsigned int* __restrict__ eidx,
                         int* __restrict__ flags) {
  int lane = threadIdx.x;  // 64 threads
  float v = bf2f(feat[2 * lane]);
  bool big = !(fabsf(v) < 1000.0f);
  unsigned long long bb = __ballot(big);
  unsigned int w = eidx[2 * lane + 1];
  unsigned long long bz = __ballot(w == 0u);
  if (lane == 0) {
    flags[0] = (__popcll(bb) < 8) ? 1 : 0;
    flags[1] = (__popcll(bz) == 64) ? 1 : 0;
  }
}

__device__ __forceinline__ int eidx_at(const int* __restrict__ p, int k, int i64) {
  return p[i64 ? (k << 1) : k];
}

// ---------- one-time fragment prep (R12, verified) ----------
__global__ __launch_bounds__(256) void k_wprep(
    const void* __restrict__ W1, const void* __restrict__ A1s,
    const void* __restrict__ A1d, const void* __restrict__ W2,
    const void* __restrict__ A2s, const void* __restrict__ A2d,
    const int* __restrict__ flags, unsigned short* __restrict__ wfH,
    unsigned short* __restrict__ wfL, unsigned short* __restrict__ baf) {
  __shared__ float Wsh[DIM * DIM];
  __shared__ float was[DIM], wad[DIM];
  const int b = blockIdx.x;  // head-matrix 0..7
  const int t = threadIdx.x;
  const int bf = flags[0];
  const void* Wv = (b < 4) ? W1 : W2;
  const void* av = (b < 4) ? A1s : A2s;
  const void* dv = (b < 4) ? A1d : A2d;
  const int hm = (b < 4) ? b : b - 4;
  for (int i = t; i < DIM * DIM; i += 256)
    Wsh[i] = bf ? bf2f(((const unsigned short*)Wv)[hm * DIM * DIM + i])
                : ((const float*)Wv)[hm * DIM * DIM + i];
  __syncthreads();
  if (t < 128) {
    int k = t & 63, isd = t >> 6;
    const void* aptr = isd ? dv : av;
    float acc = 0.f;
    for (int c = 0; c < DIM; ++c) {
      float a = bf ? bf2f(((const unsigned short*)aptr)[hm * DIM + c])
                   : ((const float*)aptr)[hm * DIM + c];
      acc = fmaf(Wsh[k * DIM + c], a, acc);
    }
    (isd ? wad : was)[k] = acc;
  }
  __syncthreads();
  // W fragments: value at (cb,ks,lane,j) = W[(32ks+8g4+j)*64 + 16cb+r16]
  for (int idx = t; idx < 512; idx += 256) {
    int lane = idx & 63, ks = (idx >> 6) & 1, cb = idx >> 7;
    int g4 = lane >> 4, r16 = lane & 15;
    int fo = (((b * 4 + cb) * 2 + ks) * 64 + lane) * 8;
#pragma unroll
    for (int j = 0; j < 8; ++j) {
      int k = 32 * ks + 8 * g4 + j;
      float w = Wsh[k * DIM + 16 * cb + r16];
      unsigned short hu = f2bf(w);
      wfH[fo + j] = hu;
      wfL[fo + j] = f2bf(w - bf2f(hu));
    }
  }
  // score fragments
  for (int idx = t; idx < 128; idx += 256) {
    int lane = idx & 63, ks = idx >> 6;
    int g4 = lane >> 4, r16 = lane & 15;
    int fo = ((b * 2 + ks) * 64 + lane) * 8;
#pragma unroll
    for (int j = 0; j < 8; ++j) {
      int k = 32 * ks + 8 * g4 + j;
      unsigned short u = 0;
      if (r16 < 4) {
        float w_ = (r16 < 2) ? was[k] : wad[k];
        unsigned short uh = f2bf(w_);
        u = (r16 & 1) ? f2bf(w_ - bf2f(uh)) : uh;
      }
      baf[fo + j] = u;
    }
  }
}

// ---------- generalized scan (n <= 65536) ----------
__global__ void k_scan1(const int* __restrict__ in, int* __restrict__ out,
                        int* __restrict__ bsum, int n) {
  __shared__ int sm[256];
  int t = threadIdx.x, b = blockIdx.x, i = b * 256 + t;
  int v = (i < n) ? in[i] : 0;
  sm[t] = v;
  __syncthreads();
  for (int off = 1; off < 256; off <<= 1) {
    int x = (t >= off) ? sm[t - off] : 0;
    __syncthreads();
    sm[t] += x;
    __syncthreads();
  }
  if (i < n) out[i] = sm[t] - v;
  if (t == 255) bsum[b] = sm[t];
}

__global__ void k_scan2(int* __restrict__ bsum, int nb) {
  __shared__ int sm[256];
  int t = threadIdx.x;
  int v = (t < nb) ? bsum[t] : 0;
  sm[t] = v;
  __syncthreads();
  for (int off = 1; off < 256; off <<= 1) {
    int x = (t >= off) ? sm[t - off] : 0;
    __syncthreads();
    sm[t] += x;
    __syncthreads();
  }
  if (t < nb) bsum[t] = sm[t] - v;
}

__global__ void k_scan3(int* __restrict__ out, const int* __restrict__ bsum, int n) {
  int t = threadIdx.x, b = blockIdx.x, i = b * 256 + t;
  if (i < n) out[i] += bsum[b];
}

// ---------- bucketed CSR build ----------
__global__ __launch_bounds__(256) void k_hist1(const int* __restrict__ eidx,
                                               const int* __restrict__ flags,
                                               int* __restrict__ hist) {
  __shared__ int h[NB];
  int t = threadIdx.x, b = blockIdx.x;
  for (int i = t; i < NB; i += 256) h[i] = 0;
  __syncthreads();
  int i64 = flags[1];
  int lo = b * CHUNK;
  for (int i = t; i < CHUNK; i += 256) {
    int d = eidx_at(eidx, N_EDGES + lo + i, i64);
    atomicAdd(&h[d >> 7], 1);
  }
  __syncthreads();
  for (int i = t; i < NB; i += 256) hist[i * NBLK + b] = h[i];
}

__global__ __launch_bounds__(256) void k_scatter(const int* __restrict__ eidx,
                                                 const int* __restrict__ flags,
                                                 const int* __restrict__ hscan,
                                                 int2* __restrict__ ebuf) {
  __shared__ int cur[NB];
  int t = threadIdx.x, b = blockIdx.x;
  for (int i = t; i < NB; i += 256) cur[i] = hscan[i * NBLK + b];
  __syncthreads();
  int i64 = flags[1];
  int lo = b * CHUNK;
  for (int i = t; i < CHUNK; i += 256) {
    int d = eidx_at(eidx, N_EDGES + lo + i, i64);
    int s = eidx_at(eidx, lo + i, i64);
    int pos = atomicAdd(&cur[d >> 7], 1);
    ebuf[pos] = make_int2(s, d);
  }
}

__global__ __launch_bounds__(256) void k_place(const int2* __restrict__ ebuf,
                                               const int* __restrict__ hscan,
                                               int* __restrict__ rowp,
                                               int* __restrict__ csr) {
  __shared__ int hcnt[128];
  __shared__ int sm[128];
  __shared__ int cur[128];
  __shared__ int lcsr[CAP];
  int t = threadIdx.x, b = blockIdx.x;
  int lo = hscan[b * NBLK];
  int hi = (b + 1 < NB) ? hscan[(b + 1) * NBLK] : N_EDGES;
  if (t < 128) hcnt[t] = 0;
  __syncthreads();
  for (int i = lo + t; i < hi; i += 256) atomicAdd(&hcnt[ebuf[i].y & 127], 1);
  __syncthreads();
  int v = (t < 128) ? hcnt[t] : 0;
  if (t < 128) sm[t] = v;
  __syncthreads();
  for (int off = 1; off < 128; off <<= 1) {
    int x = (t < 128 && t >= off) ? sm[t - off] : 0;
    __syncthreads();
    if (t < 128) sm[t] += x;
    __syncthreads();
  }
  int d0 = b * 128;
  if (t < 128) {
    int excl = sm[t] - v;  // exclusive local prefix
    cur[t] = excl;
    int d = d0 + t;
    if (d < N_NODES) rowp[d] = lo + excl;
  }
  if (b == NB - 1 && t == 0) rowp[N_NODES] = N_EDGES;
  __syncthreads();
  int seg_sz = hi - lo;
  if (seg_sz <= CAP) {
    for (int i = lo + t; i < hi; i += 256) {
      int2 pr = ebuf[i];
      int pos = atomicAdd(&cur[pr.y & 127], 1);
      lcsr[pos] = pr.x;
    }
    __syncthreads();
    for (int i = t; i < seg_sz; i += 256) csr[lo + i] = lcsr[i];
  } else {  // overflow fallback
    for (int i = lo + t; i < hi; i += 256) {
      int2 pr = ebuf[i];
      int pos = atomicAdd(&cur[pr.y & 127], 1);
      csr[lo + pos] = pr.x;
    }
  }
}

// ---------- MFMA h = x@W, layer 0 only (R15: direct feat read, R4-verified
// in-register hi/lo split — removes k_split + xh/xl round-trip) ----------
__global__ __launch_bounds__(256) void k_gemm(
    const void* __restrict__ xv,
    const unsigned short* __restrict__ wfH, const unsigned short* __restrict__ wfL,
    const unsigned short* __restrict__ baf, int mat,
    const int* __restrict__ flags, unsigned short* __restrict__ hb,
    float* __restrict__ ss, float* __restrict__ sd) {
  const int bf = flags[0];
  const int lane = threadIdx.x & 63;
  const int w = blockIdx.x * 4 + (threadIdx.x >> 6);
  const int wtile = w >> 1;
  if (wtile >= NTILES) return;
  const int cbh = (w & 1) * 2;  // col-blocks {cbh, cbh+1}
  const int r16 = lane & 15;
  const int g4 = lane >> 4;
  const int row0 = wtile * 16;

  const bf16x8* WH = (const bf16x8*)wfH;
  const bf16x8* WL = (const bf16x8*)wfL;
  bf16x8 Bh[2][2], Bl[2][2];
#pragma unroll
  for (int c = 0; c < 2; ++c)
#pragma unroll
    for (int ks = 0; ks < 2; ++ks) {
      int fi = ((mat * 4 + cbh + c) * 2 + ks) * 64 + lane;
      Bh[c][ks] = WH[fi];
      Bl[c][ks] = WL[fi];
    }

  bf16x8 Ah[2], Al[2];
  if (bf) {
    const unsigned short* xp = (const unsigned short*)xv + (row0 + r16) * DIM + 8 * g4;
#pragma unroll
    for (int ks = 0; ks < 2; ++ks) Ah[ks] = *(const bf16x8*)(xp + 32 * ks);
  } else {
    const float* xp = (const float*)xv + (row0 + r16) * DIM + 8 * g4;
#pragma unroll
    for (int ks = 0; ks < 2; ++ks) {
      float4 f0 = *(const float4*)(xp + 32 * ks);
      float4 f1 = *(const float4*)(xp + 32 * ks + 4);
      float v[8] = {f0.x, f0.y, f0.z, f0.w, f1.x, f1.y, f1.z, f1.w};
#pragma unroll
      for (int j = 0; j < 8; ++j) {
        unsigned short hu = f2bf(v[j]);
        Ah[ks][j] = (short)hu;
        Al[ks][j] = (short)f2bf(v[j] - bf2f(hu));
      }
    }
  }

  f32x4 acc[2];
#pragma unroll
  for (int c = 0; c < 2; ++c) {
    acc[c] = (f32x4){0.f, 0.f, 0.f, 0.f};
#pragma unroll
    for (int ks = 0; ks < 2; ++ks) {
      acc[c] = __builtin_amdgcn_mfma_f32_16x16x32_bf16(Ah[ks], Bh[c][ks], acc[c], 0, 0, 0);
      if (!bf)
        acc[c] = __builtin_amdgcn_mfma_f32_16x16x32_bf16(Al[ks], Bh[c][ks], acc[c], 0, 0, 0);
      acc[c] = __builtin_amdgcn_mfma_f32_16x16x32_bf16(Ah[ks], Bl[c][ks], acc[c], 0, 0, 0);
    }
  }

#pragma unroll
  for (int c = 0; c < 2; ++c)
#pragma unroll
    for (int reg = 0; reg < 4; ++reg)
      hb[(row0 + 4 * g4 + reg) * DIM + (cbh + c) * 16 + r16] = f2bf(acc[c][reg]);

  if (cbh == 0) {
    f32x4 acc2 = (f32x4){0.f, 0.f, 0.f, 0.f};
#pragma unroll
    for (int ks = 0; ks < 2; ++ks) {
      bf16x8 Ba = *(const bf16x8*)(baf + ((mat * 2 + ks) * 64 + lane) * 8);
      acc2 = __builtin_amdgcn_mfma_f32_16x16x32_bf16(Ah[ks], Ba, acc2, 0, 0, 0);
      if (!bf)
        acc2 = __builtin_amdgcn_mfma_f32_16x16x32_bf16(Al[ks], Ba, acc2, 0, 0, 0);
    }
#pragma unroll
    for (int reg = 0; reg < 4; ++reg) {
      float tmp = acc2[reg] + __shfl_xor(acc2[reg], 1);  // col pairs (0,1)/(2,3)
      int row = row0 + 4 * g4 + reg;
      if (r16 == 0) ss[row] = tmp;
      else if (r16 == 2) sd[row] = tmp;
    }
  }
}

// ---------- shared agg pieces (R5-verified) ----------
__device__ __forceinline__ void quad_accum(const unsigned short* __restrict__ hb,
                                           const int2* __restrict__ lps, int cl,
                                           int quarter, int c16, float4& acc) {
  const int quads = (cl + 3) >> 2;
#pragma unroll 4
  for (int tt = 0; tt < quads; ++tt) {
    int j = 4 * tt + quarter;  // tail entries have p=0,s=0 -> contribute 0
    int2 pv = lps[j];          // LDS broadcast within quarter-wave
    float pj = __int_as_float(pv.x);
    int sj = pv.y;
    ushort4 hv = *(const ushort4*)(hb + sj * DIM + 4 * c16);
    acc.x = fmaf(pj, bf2f(hv.x), acc.x);
    acc.y = fmaf(pj, bf2f(hv.y), acc.y);
    acc.z = fmaf(pj, bf2f(hv.z), acc.z);
    acc.w = fmaf(pj, bf2f(hv.w), acc.w);
  }
}

__device__ __forceinline__ void agg_node_big(
    const unsigned short* __restrict__ hb, const float* __restrict__ ss,
    float sdn, int base, int deg, const int* __restrict__ csr, int lane,
    int quarter, int c16, int2* __restrict__ lpw, float4& acc, float& zo) {
  float z = 0.f;
  for (int c = 0; c < deg; c += 64) {
    int j = c + lane;
    float p = 0.f; int s = 0;
    if (j < deg) {
      s = csr[base + j];
      float sc = ss[s] + sdn;
      sc = (sc >= 0.f) ? sc : 0.2f * sc;
      p = __expf(sc);
    }
    lpw[lane] = make_int2(__float_as_int(p), s);
    __builtin_amdgcn_wave_barrier();
    z += p;
    const int cl = (deg - c < 64) ? (deg - c) : 64;
    quad_accum(hb, lpw, cl, quarter, c16, acc);
    __builtin_amdgcn_wave_barrier();
  }
#pragma unroll
  for (int off = 32; off > 0; off >>= 1) z += __shfl_xor(z, off);
  zo = z;
}

// computes softmax-weighted aggregate for `node` into (ox..ow) on all lanes
// (lane's c16 selects cols 4c16..4c16+3). elu applied if do_elu.
__device__ __forceinline__ void agg_core(
    const unsigned short* __restrict__ hb, const float* __restrict__ ss,
    const float* __restrict__ sd, const int* __restrict__ rowp,
    const int* __restrict__ csr, int node, int lane, int quarter, int c16,
    int do_elu, int2* __restrict__ lpw, float& ox, float& oy, float& oz,
    float& ow) {
  const int base = rowp[node];
  const int deg = rowp[node + 1] - base;
  const float sdn = sd[node];
  float4 acc = {0.f, 0.f, 0.f, 0.f};
  float z;
  if (deg <= 64) {
    int s = 0;
    float p = 0.f;
    if (lane < deg) {
      s = csr[base + lane];
      float t = ss[s] + sdn;
      t = (t >= 0.f) ? t : 0.2f * t;
      p = __expf(t);  // shift-invariant softmax, scores O(10)
    }
    lpw[lane] = make_int2(__float_as_int(p), s);
    z = p;
    __builtin_amdgcn_wave_barrier();
    quad_accum(hb, lpw, deg, quarter, c16, acc);
    __builtin_amdgcn_wave_barrier();  // lpw reused by caller's next node
#pragma unroll
    for (int off = 32; off > 0; off >>= 1) z += __shfl_xor(z, off);
  } else {
    agg_node_big(hb, ss, sdn, base, deg, csr, lane, quarter, c16, lpw, acc, z);
  }
  acc.x += __shfl_xor(acc.x, 16);
  acc.y += __shfl_xor(acc.y, 16);
  acc.z += __shfl_xor(acc.z, 16);
  acc.w += __shfl_xor(acc.w, 16);
  acc.x += __shfl_xor(acc.x, 32);
  acc.y += __shfl_xor(acc.y, 32);
  acc.z += __shfl_xor(acc.z, 32);
  acc.w += __shfl_xor(acc.w, 32);
  float inv = 1.f / (z + 1e-16f);
  ox = acc.x * inv; oy = acc.y * inv;
  oz = acc.z * inv; ow = acc.w * inv;
  if (do_elu) {
    ox = (ox > 0.f) ? ox : expm1f(ox);
    oy = (oy > 0.f) ? oy : expm1f(oy);
    oz = (oz > 0.f) ? oz : expm1f(oz);
    ow = (ow > 0.f) ? ow : expm1f(ow);
  }
}

// ---------- R16: fused agg->gemm; batched phase-1 + INTERLEAVED 4-node gather
// loop (4 independent loads in flight) + launch_bounds(512,8) to force
// VGPR<=64 -> 8 waves/SIMD -> 4 blocks/CU (was likely 2). Per-node
// accumulation order unchanged (tt increasing) -> bit-identical results.
__global__ __launch_bounds__(512, 8) void k_fused(
    const unsigned short* __restrict__ hb_in, const float* __restrict__ ss_in,
    const float* __restrict__ sd_in, const int* __restrict__ rowp,
    const int* __restrict__ csr, const unsigned short* __restrict__ wfH,
    const unsigned short* __restrict__ wfL, const unsigned short* __restrict__ baf,
    int mat, int do_elu, unsigned short* __restrict__ hb_out,
    float* __restrict__ ss_out, float* __restrict__ sd_out) {
  __shared__ float outT[FROWS][FPAD];
  __shared__ __align__(16) int2 lps[8][4][64];  // per wave: 4 node buffers (16 KB)
  const int tid = threadIdx.x;
  const int lane = tid & 63;
  const int w = tid >> 6;  // 0..7
  const int quarter = lane >> 4;
  const int c16 = lane & 15;
  const int blk = blockIdx.x;
  const int node0 = blk * FROWS + w * 4;

  // wave-uniform row pointers (clamped: OOB nodes get deg 0)
  int bp[5];
#pragma unroll
  for (int j = 0; j < 5; ++j) {
    int idx = node0 + j;
    bp[j] = rowp[(idx < N_NODES) ? idx : N_NODES];
  }
  int deg[4];
  float sdn[4];
#pragma unroll
  for (int j = 0; j < 4; ++j) {
    deg[j] = bp[j + 1] - bp[j];
    int idx = node0 + j;
    sdn[j] = sd_in[(idx < N_NODES) ? idx : (N_NODES - 1)];
  }

  if (deg[0] <= 64 && deg[1] <= 64 && deg[2] <= 64 && deg[3] <= 64) {
    // ---- batched phase 1: 4 independent csr loads, then 4 independent ss gathers
    int s4[4];
    float p4[4];
#pragma unroll
    for (int j = 0; j < 4; ++j)
      s4[j] = (lane < deg[j]) ? csr[bp[j] + lane] : 0;
#pragma unroll
    for (int j = 0; j < 4; ++j) {
      float t = ss_in[s4[j]] + sdn[j];
      t = (t >= 0.f) ? t : 0.2f * t;
      p4[j] = (lane < deg[j]) ? __expf(t) : 0.f;
    }
#pragma unroll
    for (int j = 0; j < 4; ++j)
      lps[w][j][lane] = make_int2(__float_as_int(p4[j]), s4[j]);
    __builtin_amdgcn_wave_barrier();

    // ---- interleaved gather loop: one tt loop, 4 independent node bodies
    float4 acc[4];
#pragma unroll
    for (int j = 0; j < 4; ++j) acc[j] = (float4){0.f, 0.f, 0.f, 0.f};
    int q[4];
    int qm = 0;
#pragma unroll
    for (int j = 0; j < 4; ++j) {
      q[j] = (deg[j] + 3) >> 2;
      qm = (q[j] > qm) ? q[j] : qm;
    }
    for (int tt = 0; tt < qm; ++tt) {
      const int j4 = 4 * tt + quarter;
#pragma unroll
      for (int j = 0; j < 4; ++j) {
        if (tt < q[j]) {
          int2 pv = lps[w][j][j4];
          float pj = __int_as_float(pv.x);
          ushort4 hv = *(const ushort4*)(hb_in + pv.y * DIM + 4 * c16);
          acc[j].x = fmaf(pj, bf2f(hv.x), acc[j].x);
          acc[j].y = fmaf(pj, bf2f(hv.y), acc[j].y);
          acc[j].z = fmaf(pj, bf2f(hv.z), acc[j].z);
          acc[j].w = fmaf(pj, bf2f(hv.w), acc[j].w);
        }
      }
    }

    // ---- z reductions + epilogues
#pragma unroll
    for (int j = 0; j < 4; ++j) {
      float z = p4[j];
#pragma unroll
      for (int off = 32; off > 0; off >>= 1) z += __shfl_xor(z, off);
      float4 a = acc[j];
      a.x += __shfl_xor(a.x, 16);
      a.y += __shfl_xor(a.y, 16);
      a.z += __shfl_xor(a.z, 16);
      a.w += __shfl_xor(a.w, 16);
      a.x += __shfl_xor(a.x, 32);
      a.y += __shfl_xor(a.y, 32);
      a.z += __shfl_xor(a.z, 32);
      a.w += __shfl_xor(a.w, 32);
      float inv = 1.f / (z + 1e-16f);
      float ox = a.x * inv, oy = a.y * inv, oz = a.z * inv, ow = a.w * inv;
      if (do_elu) {
        ox = (ox > 0.f) ? ox : expm1f(ox);
        oy = (oy > 0.f) ? oy : expm1f(oy);
        oz = (oz > 0.f) ? oz : expm1f(oz);
        ow = (ow > 0.f) ? ow : expm1f(ow);
      }
      if (quarter == 0) {
        float4 o4 = {ox, oy, oz, ow};
        *(float4*)&outT[w * 4 + j][4 * c16] = o4;  // 16B-aligned
      }
    }
  } else {
    // rare path: verified per-node serial agg
    for (int j = 0; j < 4; ++j) {
      const int row = w * 4 + j;
      const int node = node0 + j;
      float ox = 0.f, oy = 0.f, oz = 0.f, ow = 0.f;
      if (node < N_NODES)
        agg_core(hb_in, ss_in, sd_in, rowp, csr, node, lane, quarter, c16,
                 do_elu, &lps[w][j][0], ox, oy, oz, ow);
      if (quarter == 0) {
        float4 o4 = {ox, oy, oz, ow};
        *(float4*)&outT[row][4 * c16] = o4;
      }
    }
  }
  __syncthreads();

  // ---- gemm phase: wave w -> tile t=w>>2 (rows t*16..+15), cb=w&3 ----
  const int t = w >> 2;
  const int cb = w & 3;
  const int r16 = c16;
  const int g4 = quarter;

  bf16x8 Ah[2], Al[2];
#pragma unroll
  for (int ks = 0; ks < 2; ++ks) {
    const float* src = &outT[t * 16 + r16][32 * ks + 8 * g4];
    float4 f0 = *(const float4*)src;
    float4 f1 = *(const float4*)(src + 4);
    float v[8] = {f0.x, f0.y, f0.z, f0.w, f1.x, f1.y, f1.z, f1.w};
#pragma unroll
    for (int jj = 0; jj < 8; ++jj) {
      unsigned short hu = f2bf(v[jj]);
      Ah[ks][jj] = (short)hu;
      Al[ks][jj] = (short)f2bf(v[jj] - bf2f(hu));
    }
  }

  const bf16x8* WH = (const bf16x8*)wfH;
  const bf16x8* WL = (const bf16x8*)wfL;
  f32x4 acc2 = (f32x4){0.f, 0.f, 0.f, 0.f};
#pragma unroll
  for (int ks = 0; ks < 2; ++ks) {
    int fi = ((mat * 4 + cb) * 2 + ks) * 64 + lane;
    bf16x8 Bh = WH[fi];
    bf16x8 Bl = WL[fi];
    acc2 = __builtin_amdgcn_mfma_f32_16x16x32_bf16(Ah[ks], Bh, acc2, 0, 0, 0);
    acc2 = __builtin_amdgcn_mfma_f32_16x16x32_bf16(Al[ks], Bh, acc2, 0, 0, 0);
    acc2 = __builtin_amdgcn_mfma_f32_16x16x32_bf16(Ah[ks], Bl, acc2, 0, 0, 0);
  }
#pragma unroll
  for (int reg = 0; reg < 4; ++reg) {
    int row = blk * FROWS + t * 16 + 4 * g4 + reg;
    if (row < N_NODES) hb_out[row * DIM + cb * 16 + r16] = f2bf(acc2[reg]);
  }

  if (cb == 0) {
    f32x4 accs = (f32x4){0.f, 0.f, 0.f, 0.f};
#pragma unroll
    for (int ks = 0; ks < 2; ++ks) {
      bf16x8 Ba = *(const bf16x8*)(baf + ((mat * 2 + ks) * 64 + lane) * 8);
      accs = __builtin_amdgcn_mfma_f32_16x16x32_bf16(Ah[ks], Ba, accs, 0, 0, 0);
      accs = __builtin_amdgcn_mfma_f32_16x16x32_bf16(Al[ks], Ba, accs, 0, 0, 0);
    }
#pragma unroll
    for (int reg = 0; reg < 4; ++reg) {
      float tmp = accs[reg] + __shfl_xor(accs[reg], 1);  // col pairs
      int row = blk * FROWS + t * 16 + 4 * g4 + reg;
      if (row < N_NODES) {
        if (r16 == 0) ss_out[row] = tmp;
        else if (r16 == 2) sd_out[row] = tmp;
      }
    }
  }
}

// ---------- final-layer agg (R5-verified single-node; is_final path) ----------
__global__ __launch_bounds__(256) void k_agg(
    const unsigned short* __restrict__ hb, const float* __restrict__ ss,
    const float* __restrict__ sd, const int* __restrict__ rowp,
    const int* __restrict__ csr, void* __restrict__ out_final,
    const int* __restrict__ flags, int do_elu) {
  __shared__ __align__(16) int2 lps[4][64];
  const int lane = threadIdx.x & 63;
  const int quarter = lane >> 4;
  const int c16 = lane & 15;
  const int w = threadIdx.x >> 6;
  const int node = blockIdx.x * 4 + w;
  float ox, oy, oz, ow;
  agg_core(hb, ss, sd, rowp, csr, node, lane, quarter, c16, do_elu,
           &lps[w][0], ox, oy, oz, ow);
  if (quarter == 0) {
    int idx = node * DIM + 4 * c16;
    if (flags[0]) {
      ushort4 o4 = {f2bf(ox), f2bf(oy), f2bf(oz), f2bf(ow)};
      *(ushort4*)((unsigned short*)out_final + idx) = o4;
    } else {
      float4 o4 = {ox, oy, oz, ow};
      *(float4*)((float*)out_final + idx) = o4;
    }
  }
}

// ---------- launch ----------
extern "C" void kernel_launch(void* const* d_in, const int* in_sizes, int n_in,
                              void* d_out, int out_size, void* d_ws, size_t ws_size,
                              hipStream_t stream) {
  const void* feat = d_in[0];
  const int* eidx = (const int*)d_in[1];

  unsigned short* hbA = (unsigned short*)d_ws;          // N*64 bf16
  unsigned short* hbB = hbA + N_NODES * DIM;            // N*64 bf16
  unsigned short* wfH = hbB + N_NODES * DIM;            // 32768
  unsigned short* wfL = wfH + 32768;                    // 32768
  unsigned short* baf = wfL + 32768;                    // 8192
  int2* ebuf = (int2*)(baf + 8192);                     // E int2
  float* ssA = (float*)(ebuf + N_EDGES);                // N
  float* sdA = ssA + N_NODES;                           // N
  float* ssB = sdA + N_NODES;                           // N
  float* sdB = ssB + N_NODES;                           // N
  int* csr  = (int*)(sdB + N_NODES);                    // E
  int* hist = csr + N_EDGES;                            // NB*NBLK
  int* hscan = hist + NB * NBLK;                        // NB*NBLK
  int* bsum = hscan + NB * NBLK;                        // 256
  int* rowp = bsum + 256;                               // N+1
  int* flags = rowp + N_NODES + 1;                      // 2

  const int NH = NB * NBLK;                 // 50048
  const int SBH = (NH + 255) / 256;         // 196

  k_detect<<<1, 64, 0, stream>>>((const unsigned short*)feat,
                                 (const unsigned int*)eidx, flags);
  k_wprep<<<8, 256, 0, stream>>>(d_in[2], d_in[3], d_in[4],
                                 d_in[5], d_in[6], d_in[7],
                                 flags, wfH, wfL, baf);
  k_hist1<<<NBLK, 256, 0, stream>>>(eidx, flags, hist);
  k_scan1<<<SBH, 256, 0, stream>>>(hist, hscan, bsum, NH);
  k_scan2<<<1, 256, 0, stream>>>(bsum, SBH);
  k_scan3<<<SBH, 256, 0, stream>>>(hscan, bsum, NH);
  k_scatter<<<NBLK, 256, 0, stream>>>(eidx, flags, hscan, ebuf);
  k_place<<<NB, 256, 0, stream>>>(ebuf, hscan, rowp, csr);

  const int GB = (2 * NTILES + 3) / 4;              // layer-0 gemm
  const int FB = (N_NODES + FROWS - 1) / FROWS;     // 1563 fused blocks

  // layer 0 gemm: features -> hbA, ssA, sdA (direct feat read)
  k_gemm<<<GB, 256, 0, stream>>>(feat, wfH, wfL, baf, 0, flags, hbA, ssA, sdA);

  // 7 fused layers: agg(k) + gemm(k+1). X_0 = A; alternate.
  for (int k = 0; k < 7; ++k) {
    const unsigned short* hin = (k & 1) ? hbB : hbA;
    const float* sin_ = (k & 1) ? ssB : ssA;
    const float* din = (k & 1) ? sdB : sdA;
    unsigned short* hout = (k & 1) ? hbA : hbB;
    float* sout = (k & 1) ? ssA : ssB;
    float* dout = (k & 1) ? sdA : sdB;
    k_fused<<<FB, 512, 0, stream>>>(hin, sin_, din, rowp, csr, wfH, wfL, baf,
                                    k + 1, (k == 3) ? 1 : 0, hout, sout, dout);
  }

  // final agg (layer 7): X_7 = B (7 fused flips from A)
  k_agg<<<N_NODES / 4, 256, 0, stream>>>(hbB, ssB, sdB, rowp, csr, d_out,
                                         flags, 1);
}

// Round 14
// 380.824 us; speedup vs baseline: 1.0160x; 1.0160x over previous
//
#include <hip/hip_runtime.h>
#include <hip/hip_bf16.h>

#define N_NODES 50000
#define N_EDGES 800000
#define DIM 64
#define NB 391      // dst buckets of 128 nodes: ceil(50000/128)
#define NBLK 128    // blocks in bucketize pass
#define CHUNK 6250  // N_EDGES / NBLK (exact)
#define CAP 4096    // LDS staging capacity per bucket segment (avg ~2048)
#define NTILES 3125 // 50000 / 16 row-tiles (exact)
#define FROWS 32    // fused kernel: rows (nodes) per block
#define FPAD 68     // LDS row stride (floats): 16B-aligned, 68%32=4 -> 2-way banks

typedef __attribute__((ext_vector_type(8))) short bf16x8;
typedef __attribute__((ext_vector_type(4))) float f32x4;

// ---------- helpers ----------
__device__ __forceinline__ float bf2f(unsigned short u) {
  return __uint_as_float(((unsigned int)u) << 16);
}
__device__ __forceinline__ unsigned short f2bf(float f) {
  unsigned int x = __float_as_uint(f);
  unsigned int r = (x + 0x7fffu + ((x >> 16) & 1u)) >> 16;  // RNE
  return (unsigned short)r;
}

// ---------- dtype detection (flags[0]=bf16 inputs, flags[1]=int64 indices) ----------
__global__ void k_detect(const unsigned short* __restrict__ feat,
                         const unsigned int* __restrict__ eidx,
                         int* __restrict__ flags) {
  int lane = threadIdx.x;  // 64 threads
  float v = bf2f(feat[2 * lane]);
  bool big = !(fabsf(v) < 1000.0f);
  unsigned long long bb = __ballot(big);
  unsigned int w = eidx[2 * lane + 1];
  unsigned long long bz = __ballot(w == 0u);
  if (lane == 0) {
    flags[0] = (__popcll(bb) < 8) ? 1 : 0;
    flags[1] = (__popcll(bz) == 64) ? 1 : 0;
  }
}

__device__ __forceinline__ int eidx_at(const int* __restrict__ p, int k, int i64) {
  return p[i64 ? (k << 1) : k];
}

// ---------- one-time fragment prep (R12, verified) ----------
__global__ __launch_bounds__(256) void k_wprep(
    const void* __restrict__ W1, const void* __restrict__ A1s,
    const void* __restrict__ A1d, const void* __restrict__ W2,
    const void* __restrict__ A2s, const void* __restrict__ A2d,
    const int* __restrict__ flags, unsigned short* __restrict__ wfH,
    unsigned short* __restrict__ wfL, unsigned short* __restrict__ baf) {
  __shared__ float Wsh[DIM * DIM];
  __shared__ float was[DIM], wad[DIM];
  const int b = blockIdx.x;  // head-matrix 0..7
  const int t = threadIdx.x;
  const int bf = flags[0];
  const void* Wv = (b < 4) ? W1 : W2;
  const void* av = (b < 4) ? A1s : A2s;
  const void* dv = (b < 4) ? A1d : A2d;
  const int hm = (b < 4) ? b : b - 4;
  for (int i = t; i < DIM * DIM; i += 256)
    Wsh[i] = bf ? bf2f(((const unsigned short*)Wv)[hm * DIM * DIM + i])
                : ((const float*)Wv)[hm * DIM * DIM + i];
  __syncthreads();
  if (t < 128) {
    int k = t & 63, isd = t >> 6;
    const void* aptr = isd ? dv : av;
    float acc = 0.f;
    for (int c = 0; c < DIM; ++c) {
      float a = bf ? bf2f(((const unsigned short*)aptr)[hm * DIM + c])
                   : ((const float*)aptr)[hm * DIM + c];
      acc = fmaf(Wsh[k * DIM + c], a, acc);
    }
    (isd ? wad : was)[k] = acc;
  }
  __syncthreads();
  // W fragments: value at (cb,ks,lane,j) = W[(32ks+8g4+j)*64 + 16cb+r16]
  for (int idx = t; idx < 512; idx += 256) {
    int lane = idx & 63, ks = (idx >> 6) & 1, cb = idx >> 7;
    int g4 = lane >> 4, r16 = lane & 15;
    int fo = (((b * 4 + cb) * 2 + ks) * 64 + lane) * 8;
#pragma unroll
    for (int j = 0; j < 8; ++j) {
      int k = 32 * ks + 8 * g4 + j;
      float w = Wsh[k * DIM + 16 * cb + r16];
      unsigned short hu = f2bf(w);
      wfH[fo + j] = hu;
      wfL[fo + j] = f2bf(w - bf2f(hu));
    }
  }
  // score fragments
  for (int idx = t; idx < 128; idx += 256) {
    int lane = idx & 63, ks = idx >> 6;
    int g4 = lane >> 4, r16 = lane & 15;
    int fo = ((b * 2 + ks) * 64 + lane) * 8;
#pragma unroll
    for (int j = 0; j < 8; ++j) {
      int k = 32 * ks + 8 * g4 + j;
      unsigned short u = 0;
      if (r16 < 4) {
        float w_ = (r16 < 2) ? was[k] : wad[k];
        unsigned short uh = f2bf(w_);
        u = (r16 & 1) ? f2bf(w_ - bf2f(uh)) : uh;
      }
      baf[fo + j] = u;
    }
  }
}

// ---------- generalized scan (n <= 65536) ----------
__global__ void k_scan1(const int* __restrict__ in, int* __restrict__ out,
                        int* __restrict__ bsum, int n) {
  __shared__ int sm[256];
  int t = threadIdx.x, b = blockIdx.x, i = b * 256 + t;
  int v = (i < n) ? in[i] : 0;
  sm[t] = v;
  __syncthreads();
  for (int off = 1; off < 256; off <<= 1) {
    int x = (t >= off) ? sm[t - off] : 0;
    __syncthreads();
    sm[t] += x;
    __syncthreads();
  }
  if (i < n) out[i] = sm[t] - v;
  if (t == 255) bsum[b] = sm[t];
}

__global__ void k_scan2(int* __restrict__ bsum, int nb) {
  __shared__ int sm[256];
  int t = threadIdx.x;
  int v = (t < nb) ? bsum[t] : 0;
  sm[t] = v;
  __syncthreads();
  for (int off = 1; off < 256; off <<= 1) {
    int x = (t >= off) ? sm[t - off] : 0;
    __syncthreads();
    sm[t] += x;
    __syncthreads();
  }
  if (t < nb) bsum[t] = sm[t] - v;
}

__global__ void k_scan3(int* __restrict__ out, const int* __restrict__ bsum, int n) {
  int t = threadIdx.x, b = blockIdx.x, i = b * 256 + t;
  if (i < n) out[i] += bsum[b];
}

// ---------- bucketed CSR build ----------
__global__ __launch_bounds__(256) void k_hist1(const int* __restrict__ eidx,
                                               const int* __restrict__ flags,
                                               int* __restrict__ hist) {
  __shared__ int h[NB];
  int t = threadIdx.x, b = blockIdx.x;
  for (int i = t; i < NB; i += 256) h[i] = 0;
  __syncthreads();
  int i64 = flags[1];
  int lo = b * CHUNK;
  for (int i = t; i < CHUNK; i += 256) {
    int d = eidx_at(eidx, N_EDGES + lo + i, i64);
    atomicAdd(&h[d >> 7], 1);
  }
  __syncthreads();
  for (int i = t; i < NB; i += 256) hist[i * NBLK + b] = h[i];
}

__global__ __launch_bounds__(256) void k_scatter(const int* __restrict__ eidx,
                                                 const int* __restrict__ flags,
                                                 const int* __restrict__ hscan,
                                                 int2* __restrict__ ebuf) {
  __shared__ int cur[NB];
  int t = threadIdx.x, b = blockIdx.x;
  for (int i = t; i < NB; i += 256) cur[i] = hscan[i * NBLK + b];
  __syncthreads();
  int i64 = flags[1];
  int lo = b * CHUNK;
  for (int i = t; i < CHUNK; i += 256) {
    int d = eidx_at(eidx, N_EDGES + lo + i, i64);
    int s = eidx_at(eidx, lo + i, i64);
    int pos = atomicAdd(&cur[d >> 7], 1);
    ebuf[pos] = make_int2(s, d);
  }
}

__global__ __launch_bounds__(256) void k_place(const int2* __restrict__ ebuf,
                                               const int* __restrict__ hscan,
                                               int* __restrict__ rowp,
                                               int* __restrict__ csr) {
  __shared__ int hcnt[128];
  __shared__ int sm[128];
  __shared__ int cur[128];
  __shared__ int lcsr[CAP];
  int t = threadIdx.x, b = blockIdx.x;
  int lo = hscan[b * NBLK];
  int hi = (b + 1 < NB) ? hscan[(b + 1) * NBLK] : N_EDGES;
  if (t < 128) hcnt[t] = 0;
  __syncthreads();
  for (int i = lo + t; i < hi; i += 256) atomicAdd(&hcnt[ebuf[i].y & 127], 1);
  __syncthreads();
  int v = (t < 128) ? hcnt[t] : 0;
  if (t < 128) sm[t] = v;
  __syncthreads();
  for (int off = 1; off < 128; off <<= 1) {
    int x = (t < 128 && t >= off) ? sm[t - off] : 0;
    __syncthreads();
    if (t < 128) sm[t] += x;
    __syncthreads();
  }
  int d0 = b * 128;
  if (t < 128) {
    int excl = sm[t] - v;  // exclusive local prefix
    cur[t] = excl;
    int d = d0 + t;
    if (d < N_NODES) rowp[d] = lo + excl;
  }
  if (b == NB - 1 && t == 0) rowp[N_NODES] = N_EDGES;
  __syncthreads();
  int seg_sz = hi - lo;
  if (seg_sz <= CAP) {
    for (int i = lo + t; i < hi; i += 256) {
      int2 pr = ebuf[i];
      int pos = atomicAdd(&cur[pr.y & 127], 1);
      lcsr[pos] = pr.x;
    }
    __syncthreads();
    for (int i = t; i < seg_sz; i += 256) csr[lo + i] = lcsr[i];
  } else {  // overflow fallback
    for (int i = lo + t; i < hi; i += 256) {
      int2 pr = ebuf[i];
      int pos = atomicAdd(&cur[pr.y & 127], 1);
      csr[lo + pos] = pr.x;
    }
  }
}

// ---------- MFMA h = x@W, layer 0 only (R15: direct feat read, R4-verified
// in-register hi/lo split — removes k_split + xh/xl round-trip) ----------
__global__ __launch_bounds__(256) void k_gemm(
    const void* __restrict__ xv,
    const unsigned short* __restrict__ wfH, const unsigned short* __restrict__ wfL,
    const unsigned short* __restrict__ baf, int mat,
    const int* __restrict__ flags, unsigned short* __restrict__ hb,
    float* __restrict__ ss, float* __restrict__ sd) {
  const int bf = flags[0];
  const int lane = threadIdx.x & 63;
  const int w = blockIdx.x * 4 + (threadIdx.x >> 6);
  const int wtile = w >> 1;
  if (wtile >= NTILES) return;
  const int cbh = (w & 1) * 2;  // col-blocks {cbh, cbh+1}
  const int r16 = lane & 15;
  const int g4 = lane >> 4;
  const int row0 = wtile * 16;

  const bf16x8* WH = (const bf16x8*)wfH;
  const bf16x8* WL = (const bf16x8*)wfL;
  bf16x8 Bh[2][2], Bl[2][2];
#pragma unroll
  for (int c = 0; c < 2; ++c)
#pragma unroll
    for (int ks = 0; ks < 2; ++ks) {
      int fi = ((mat * 4 + cbh + c) * 2 + ks) * 64 + lane;
      Bh[c][ks] = WH[fi];
      Bl[c][ks] = WL[fi];
    }

  bf16x8 Ah[2], Al[2];
  if (bf) {
    const unsigned short* xp = (const unsigned short*)xv + (row0 + r16) * DIM + 8 * g4;
#pragma unroll
    for (int ks = 0; ks < 2; ++ks) Ah[ks] = *(const bf16x8*)(xp + 32 * ks);
  } else {
    const float* xp = (const float*)xv + (row0 + r16) * DIM + 8 * g4;
#pragma unroll
    for (int ks = 0; ks < 2; ++ks) {
      float4 f0 = *(const float4*)(xp + 32 * ks);
      float4 f1 = *(const float4*)(xp + 32 * ks + 4);
      float v[8] = {f0.x, f0.y, f0.z, f0.w, f1.x, f1.y, f1.z, f1.w};
#pragma unroll
      for (int j = 0; j < 8; ++j) {
        unsigned short hu = f2bf(v[j]);
        Ah[ks][j] = (short)hu;
        Al[ks][j] = (short)f2bf(v[j] - bf2f(hu));
      }
    }
  }

  f32x4 acc[2];
#pragma unroll
  for (int c = 0; c < 2; ++c) {
    acc[c] = (f32x4){0.f, 0.f, 0.f, 0.f};
#pragma unroll
    for (int ks = 0; ks < 2; ++ks) {
      acc[c] = __builtin_amdgcn_mfma_f32_16x16x32_bf16(Ah[ks], Bh[c][ks], acc[c], 0, 0, 0);
      if (!bf)
        acc[c] = __builtin_amdgcn_mfma_f32_16x16x32_bf16(Al[ks], Bh[c][ks], acc[c], 0, 0, 0);
      acc[c] = __builtin_amdgcn_mfma_f32_16x16x32_bf16(Ah[ks], Bl[c][ks], acc[c], 0, 0, 0);
    }
  }

#pragma unroll
  for (int c = 0; c < 2; ++c)
#pragma unroll
    for (int reg = 0; reg < 4; ++reg)
      hb[(row0 + 4 * g4 + reg) * DIM + (cbh + c) * 16 + r16] = f2bf(acc[c][reg]);

  if (cbh == 0) {
    f32x4 acc2 = (f32x4){0.f, 0.f, 0.f, 0.f};
#pragma unroll
    for (int ks = 0; ks < 2; ++ks) {
      bf16x8 Ba = *(const bf16x8*)(baf + ((mat * 2 + ks) * 64 + lane) * 8);
      acc2 = __builtin_amdgcn_mfma_f32_16x16x32_bf16(Ah[ks], Ba, acc2, 0, 0, 0);
      if (!bf)
        acc2 = __builtin_amdgcn_mfma_f32_16x16x32_bf16(Al[ks], Ba, acc2, 0, 0, 0);
    }
#pragma unroll
    for (int reg = 0; reg < 4; ++reg) {
      float tmp = acc2[reg] + __shfl_xor(acc2[reg], 1);  // col pairs (0,1)/(2,3)
      int row = row0 + 4 * g4 + reg;
      if (r16 == 0) ss[row] = tmp;
      else if (r16 == 2) sd[row] = tmp;
    }
  }
}

// ---------- shared agg pieces (R5-verified) ----------
__device__ __forceinline__ void quad_accum(const unsigned short* __restrict__ hb,
                                           const int2* __restrict__ lps, int cl,
                                           int quarter, int c16, float4& acc) {
  const int quads = (cl + 3) >> 2;
#pragma unroll 4
  for (int tt = 0; tt < quads; ++tt) {
    int j = 4 * tt + quarter;  // tail entries have p=0,s=0 -> contribute 0
    int2 pv = lps[j];          // LDS broadcast within quarter-wave
    float pj = __int_as_float(pv.x);
    int sj = pv.y;
    ushort4 hv = *(const ushort4*)(hb + sj * DIM + 4 * c16);
    acc.x = fmaf(pj, bf2f(hv.x), acc.x);
    acc.y = fmaf(pj, bf2f(hv.y), acc.y);
    acc.z = fmaf(pj, bf2f(hv.z), acc.z);
    acc.w = fmaf(pj, bf2f(hv.w), acc.w);
  }
}

__device__ __forceinline__ void agg_node_big(
    const unsigned short* __restrict__ hb, const float* __restrict__ ss,
    float sdn, int base, int deg, const int* __restrict__ csr, int lane,
    int quarter, int c16, int2* __restrict__ lpw, float4& acc, float& zo) {
  float z = 0.f;
  for (int c = 0; c < deg; c += 64) {
    int j = c + lane;
    float p = 0.f; int s = 0;
    if (j < deg) {
      s = csr[base + j];
      float sc = ss[s] + sdn;
      sc = (sc >= 0.f) ? sc : 0.2f * sc;
      p = __expf(sc);
    }
    lpw[lane] = make_int2(__float_as_int(p), s);
    __builtin_amdgcn_wave_barrier();
    z += p;
    const int cl = (deg - c < 64) ? (deg - c) : 64;
    quad_accum(hb, lpw, cl, quarter, c16, acc);
    __builtin_amdgcn_wave_barrier();
  }
#pragma unroll
  for (int off = 32; off > 0; off >>= 1) z += __shfl_xor(z, off);
  zo = z;
}

// computes softmax-weighted aggregate for `node` into (ox..ow) on all lanes
// (lane's c16 selects cols 4c16..4c16+3). elu applied if do_elu.
__device__ __forceinline__ void agg_core(
    const unsigned short* __restrict__ hb, const float* __restrict__ ss,
    const float* __restrict__ sd, const int* __restrict__ rowp,
    const int* __restrict__ csr, int node, int lane, int quarter, int c16,
    int do_elu, int2* __restrict__ lpw, float& ox, float& oy, float& oz,
    float& ow) {
  const int base = rowp[node];
  const int deg = rowp[node + 1] - base;
  const float sdn = sd[node];
  float4 acc = {0.f, 0.f, 0.f, 0.f};
  float z;
  if (deg <= 64) {
    int s = 0;
    float p = 0.f;
    if (lane < deg) {
      s = csr[base + lane];
      float t = ss[s] + sdn;
      t = (t >= 0.f) ? t : 0.2f * t;
      p = __expf(t);  // shift-invariant softmax, scores O(10)
    }
    lpw[lane] = make_int2(__float_as_int(p), s);
    z = p;
    __builtin_amdgcn_wave_barrier();
    quad_accum(hb, lpw, deg, quarter, c16, acc);
    __builtin_amdgcn_wave_barrier();  // lpw reused by caller's next node
#pragma unroll
    for (int off = 32; off > 0; off >>= 1) z += __shfl_xor(z, off);
  } else {
    agg_node_big(hb, ss, sdn, base, deg, csr, lane, quarter, c16, lpw, acc, z);
  }
  acc.x += __shfl_xor(acc.x, 16);
  acc.y += __shfl_xor(acc.y, 16);
  acc.z += __shfl_xor(acc.z, 16);
  acc.w += __shfl_xor(acc.w, 16);
  acc.x += __shfl_xor(acc.x, 32);
  acc.y += __shfl_xor(acc.y, 32);
  acc.z += __shfl_xor(acc.z, 32);
  acc.w += __shfl_xor(acc.w, 32);
  float inv = 1.f / (z + 1e-16f);
  ox = acc.x * inv; oy = acc.y * inv;
  oz = acc.z * inv; ow = acc.w * inv;
  if (do_elu) {
    ox = (ox > 0.f) ? ox : expm1f(ox);
    oy = (oy > 0.f) ? oy : expm1f(oy);
    oz = (oz > 0.f) ? oz : expm1f(oz);
    ow = (ow > 0.f) ? ow : expm1f(ow);
  }
}

// ---------- R17: fused agg->gemm; batched phase-1 + interleaved 4-node gather
// loop. launch_bounds(512,4): R13's (512,8) forced VGPR=32 -> scratch spills
// -> 44us/dispatch + 141us cold (counter-verified). (512,4) caps at 128 VGPR
// (no spills, 2 blocks/CU — R12 regime) while keeping the interleave.
__global__ __launch_bounds__(512, 4) void k_fused(
    const unsigned short* __restrict__ hb_in, const float* __restrict__ ss_in,
    const float* __restrict__ sd_in, const int* __restrict__ rowp,
    const int* __restrict__ csr, const unsigned short* __restrict__ wfH,
    const unsigned short* __restrict__ wfL, const unsigned short* __restrict__ baf,
    int mat, int do_elu, unsigned short* __restrict__ hb_out,
    float* __restrict__ ss_out, float* __restrict__ sd_out) {
  __shared__ float outT[FROWS][FPAD];
  __shared__ __align__(16) int2 lps[8][4][64];  // per wave: 4 node buffers (16 KB)
  const int tid = threadIdx.x;
  const int lane = tid & 63;
  const int w = tid >> 6;  // 0..7
  const int quarter = lane >> 4;
  const int c16 = lane & 15;
  const int blk = blockIdx.x;
  const int node0 = blk * FROWS + w * 4;

  // wave-uniform row pointers (clamped: OOB nodes get deg 0)
  int bp[5];
#pragma unroll
  for (int j = 0; j < 5; ++j) {
    int idx = node0 + j;
    bp[j] = rowp[(idx < N_NODES) ? idx : N_NODES];
  }
  int deg[4];
  float sdn[4];
#pragma unroll
  for (int j = 0; j < 4; ++j) {
    deg[j] = bp[j + 1] - bp[j];
    int idx = node0 + j;
    sdn[j] = sd_in[(idx < N_NODES) ? idx : (N_NODES - 1)];
  }

  if (deg[0] <= 64 && deg[1] <= 64 && deg[2] <= 64 && deg[3] <= 64) {
    // ---- batched phase 1: 4 independent csr loads, then 4 independent ss gathers
    int s4[4];
    float p4[4];
#pragma unroll
    for (int j = 0; j < 4; ++j)
      s4[j] = (lane < deg[j]) ? csr[bp[j] + lane] : 0;
#pragma unroll
    for (int j = 0; j < 4; ++j) {
      float t = ss_in[s4[j]] + sdn[j];
      t = (t >= 0.f) ? t : 0.2f * t;
      p4[j] = (lane < deg[j]) ? __expf(t) : 0.f;
    }
#pragma unroll
    for (int j = 0; j < 4; ++j)
      lps[w][j][lane] = make_int2(__float_as_int(p4[j]), s4[j]);
    __builtin_amdgcn_wave_barrier();

    // ---- interleaved gather loop: one tt loop, 4 independent node bodies
    float4 acc[4];
#pragma unroll
    for (int j = 0; j < 4; ++j) acc[j] = (float4){0.f, 0.f, 0.f, 0.f};
    int q[4];
    int qm = 0;
#pragma unroll
    for (int j = 0; j < 4; ++j) {
      q[j] = (deg[j] + 3) >> 2;
      qm = (q[j] > qm) ? q[j] : qm;
    }
    for (int tt = 0; tt < qm; ++tt) {
      const int j4 = 4 * tt + quarter;
#pragma unroll
      for (int j = 0; j < 4; ++j) {
        if (tt < q[j]) {
          int2 pv = lps[w][j][j4];
          float pj = __int_as_float(pv.x);
          ushort4 hv = *(const ushort4*)(hb_in + pv.y * DIM + 4 * c16);
          acc[j].x = fmaf(pj, bf2f(hv.x), acc[j].x);
          acc[j].y = fmaf(pj, bf2f(hv.y), acc[j].y);
          acc[j].z = fmaf(pj, bf2f(hv.z), acc[j].z);
          acc[j].w = fmaf(pj, bf2f(hv.w), acc[j].w);
        }
      }
    }

    // ---- z reductions + epilogues
#pragma unroll
    for (int j = 0; j < 4; ++j) {
      float z = p4[j];
#pragma unroll
      for (int off = 32; off > 0; off >>= 1) z += __shfl_xor(z, off);
      float4 a = acc[j];
      a.x += __shfl_xor(a.x, 16);
      a.y += __shfl_xor(a.y, 16);
      a.z += __shfl_xor(a.z, 16);
      a.w += __shfl_xor(a.w, 16);
      a.x += __shfl_xor(a.x, 32);
      a.y += __shfl_xor(a.y, 32);
      a.z += __shfl_xor(a.z, 32);
      a.w += __shfl_xor(a.w, 32);
      float inv = 1.f / (z + 1e-16f);
      float ox = a.x * inv, oy = a.y * inv, oz = a.z * inv, ow = a.w * inv;
      if (do_elu) {
        ox = (ox > 0.f) ? ox : expm1f(ox);
        oy = (oy > 0.f) ? oy : expm1f(oy);
        oz = (oz > 0.f) ? oz : expm1f(oz);
        ow = (ow > 0.f) ? ow : expm1f(ow);
      }
      if (quarter == 0) {
        float4 o4 = {ox, oy, oz, ow};
        *(float4*)&outT[w * 4 + j][4 * c16] = o4;  // 16B-aligned
      }
    }
  } else {
    // rare path: verified per-node serial agg
    for (int j = 0; j < 4; ++j) {
      const int row = w * 4 + j;
      const int node = node0 + j;
      float ox = 0.f, oy = 0.f, oz = 0.f, ow = 0.f;
      if (node < N_NODES)
        agg_core(hb_in, ss_in, sd_in, rowp, csr, node, lane, quarter, c16,
                 do_elu, &lps[w][j][0], ox, oy, oz, ow);
      if (quarter == 0) {
        float4 o4 = {ox, oy, oz, ow};
        *(float4*)&outT[row][4 * c16] = o4;
      }
    }
  }
  __syncthreads();

  // ---- gemm phase: wave w -> tile t=w>>2 (rows t*16..+15), cb=w&3 ----
  const int t = w >> 2;
  const int cb = w & 3;
  const int r16 = c16;
  const int g4 = quarter;

  bf16x8 Ah[2], Al[2];
#pragma unroll
  for (int ks = 0; ks < 2; ++ks) {
    const float* src = &outT[t * 16 + r16][32 * ks + 8 * g4];
    float4 f0 = *(const float4*)src;
    float4 f1 = *(const float4*)(src + 4);
    float v[8] = {f0.x, f0.y, f0.z, f0.w, f1.x, f1.y, f1.z, f1.w};
#pragma unroll
    for (int jj = 0; jj < 8; ++jj) {
      unsigned short hu = f2bf(v[jj]);
      Ah[ks][jj] = (short)hu;
      Al[ks][jj] = (short)f2bf(v[jj] - bf2f(hu));
    }
  }

  const bf16x8* WH = (const bf16x8*)wfH;
  const bf16x8* WL = (const bf16x8*)wfL;
  f32x4 acc2 = (f32x4){0.f, 0.f, 0.f, 0.f};
#pragma unroll
  for (int ks = 0; ks < 2; ++ks) {
    int fi = ((mat * 4 + cb) * 2 + ks) * 64 + lane;
    bf16x8 Bh = WH[fi];
    bf16x8 Bl = WL[fi];
    acc2 = __builtin_amdgcn_mfma_f32_16x16x32_bf16(Ah[ks], Bh, acc2, 0, 0, 0);
    acc2 = __builtin_amdgcn_mfma_f32_16x16x32_bf16(Al[ks], Bh, acc2, 0, 0, 0);
    acc2 = __builtin_amdgcn_mfma_f32_16x16x32_bf16(Ah[ks], Bl, acc2, 0, 0, 0);
  }
#pragma unroll
  for (int reg = 0; reg < 4; ++reg) {
    int row = blk * FROWS + t * 16 + 4 * g4 + reg;
    if (row < N_NODES) hb_out[row * DIM + cb * 16 + r16] = f2bf(acc2[reg]);
  }

  if (cb == 0) {
    f32x4 accs = (f32x4){0.f, 0.f, 0.f, 0.f};
#pragma unroll
    for (int ks = 0; ks < 2; ++ks) {
      bf16x8 Ba = *(const bf16x8*)(baf + ((mat * 2 + ks) * 64 + lane) * 8);
      accs = __builtin_amdgcn_mfma_f32_16x16x32_bf16(Ah[ks], Ba, accs, 0, 0, 0);
      accs = __builtin_amdgcn_mfma_f32_16x16x32_bf16(Al[ks], Ba, accs, 0, 0, 0);
    }
#pragma unroll
    for (int reg = 0; reg < 4; ++reg) {
      float tmp = accs[reg] + __shfl_xor(accs[reg], 1);  // col pairs
      int row = blk * FROWS + t * 16 + 4 * g4 + reg;
      if (row < N_NODES) {
        if (r16 == 0) ss_out[row] = tmp;
        else if (r16 == 2) sd_out[row] = tmp;
      }
    }
  }
}

// ---------- final-layer agg (R5-verified single-node; is_final path) ----------
__global__ __launch_bounds__(256) void k_agg(
    const unsigned short* __restrict__ hb, const float* __restrict__ ss,
    const float* __restrict__ sd, const int* __restrict__ rowp,
    const int* __restrict__ csr, void* __restrict__ out_final,
    const int* __restrict__ flags, int do_elu) {
  __shared__ __align__(16) int2 lps[4][64];
  const int lane = threadIdx.x & 63;
  const int quarter = lane >> 4;
  const int c16 = lane & 15;
  const int w = threadIdx.x >> 6;
  const int node = blockIdx.x * 4 + w;
  float ox, oy, oz, ow;
  agg_core(hb, ss, sd, rowp, csr, node, lane, quarter, c16, do_elu,
           &lps[w][0], ox, oy, oz, ow);
  if (quarter == 0) {
    int idx = node * DIM + 4 * c16;
    if (flags[0]) {
      ushort4 o4 = {f2bf(ox), f2bf(oy), f2bf(oz), f2bf(ow)};
      *(ushort4*)((unsigned short*)out_final + idx) = o4;
    } else {
      float4 o4 = {ox, oy, oz, ow};
      *(float4*)((float*)out_final + idx) = o4;
    }
  }
}

// ---------- launch ----------
extern "C" void kernel_launch(void* const* d_in, const int* in_sizes, int n_in,
                              void* d_out, int out_size, void* d_ws, size_t ws_size,
                              hipStream_t stream) {
  const void* feat = d_in[0];
  const int* eidx = (const int*)d_in[1];

  unsigned short* hbA = (unsigned short*)d_ws;          // N*64 bf16
  unsigned short* hbB = hbA + N_NODES * DIM;            // N*64 bf16
  unsigned short* wfH = hbB + N_NODES * DIM;            // 32768
  unsigned short* wfL = wfH + 32768;                    // 32768
  unsigned short* baf = wfL + 32768;                    // 8192
  int2* ebuf = (int2*)(baf + 8192);                     // E int2
  float* ssA = (float*)(ebuf + N_EDGES);                // N
  float* sdA = ssA + N_NODES;                           // N
  float* ssB = sdA + N_NODES;                           // N
  float* sdB = ssB + N_NODES;                           // N
  int* csr  = (int*)(sdB + N_NODES);                    // E
  int* hist = csr + N_EDGES;                            // NB*NBLK
  int* hscan = hist + NB * NBLK;                        // NB*NBLK
  int* bsum = hscan + NB * NBLK;                        // 256
  int* rowp = bsum + 256;                               // N+1
  int* flags = rowp + N_NODES + 1;                      // 2

  const int NH = NB * NBLK;                 // 50048
  const int SBH = (NH + 255) / 256;         // 196

  k_detect<<<1, 64, 0, stream>>>((const unsigned short*)feat,
                                 (const unsigned int*)eidx, flags);
  k_wprep<<<8, 256, 0, stream>>>(d_in[2], d_in[3], d_in[4],
                                 d_in[5], d_in[6], d_in[7],
                                 flags, wfH, wfL, baf);
  k_hist1<<<NBLK, 256, 0, stream>>>(eidx, flags, hist);
  k_scan1<<<SBH, 256, 0, stream>>>(hist, hscan, bsum, NH);
  k_scan2<<<1, 256, 0, stream>>>(bsum, SBH);
  k_scan3<<<SBH, 256, 0, stream>>>(hscan, bsum, NH);
  k_scatter<<<NBLK, 256, 0, stream>>>(eidx, flags, hscan, ebuf);
  k_place<<<NB, 256, 0, stream>>>(ebuf, hscan, rowp, csr);

  const int GB = (2 * NTILES + 3) / 4;              // layer-0 gemm
  const int FB = (N_NODES + FROWS - 1) / FROWS;     // 1563 fused blocks

  // layer 0 gemm: features -> hbA, ssA, sdA (direct feat read)
  k_gemm<<<GB, 256, 0, stream>>>(feat, wfH, wfL, baf, 0, flags, hbA, ssA, sdA);

  // 7 fused layers: agg(k) + gemm(k+1). X_0 = A; alternate.
  for (int k = 0; k < 7; ++k) {
    const unsigned short* hin = (k & 1) ? hbB : hbA;
    const float* sin_ = (k & 1) ? ssB : ssA;
    const float* din = (k & 1) ? sdB : sdA;
    unsigned short* hout = (k & 1) ? hbA : hbB;
    float* sout = (k & 1) ? ssA : ssB;
    float* dout = (k & 1) ? sdA : sdB;
    k_fused<<<FB, 512, 0, stream>>>(hin, sin_, din, rowp, csr, wfH, wfL, baf,
                                    k + 1, (k == 3) ? 1 : 0, hout, sout, dout);
  }

  // final agg (layer 7): X_7 = B (7 fused flips from A)
  k_agg<<<N_NODES / 4, 256, 0, stream>>>(hbB, ssB, sdB, rowp, csr, d_out,
                                         flags, 1);
}

// Round 22
// 349.152 us; speedup vs baseline: 1.1082x; 1.0907x over previous
//
#include <hip/hip_runtime.h>
#include <hip/hip_bf16.h>

#define N_NODES 50000
#define N_EDGES 800000
#define DIM 64
#define NB 391      // dst buckets of 128 nodes: ceil(50000/128)
#define NBLK 128    // blocks in bucketize pass
#define CHUNK 6250  // N_EDGES / NBLK (exact)
#define CAP 4096    // LDS staging capacity per bucket segment (avg ~2048)
#define NTILES 3125 // 50000 / 16 row-tiles (exact)
#define FROWS 32    // fused kernel: rows (nodes) per block
#define FPAD 68     // LDS row stride (floats): 16B-aligned, 68%32=4 -> 2-way banks

typedef __attribute__((ext_vector_type(8))) short bf16x8;
typedef __attribute__((ext_vector_type(4))) float f32x4;

// ---------- helpers ----------
__device__ __forceinline__ float bf2f(unsigned short u) {
  return __uint_as_float(((unsigned int)u) << 16);
}
__device__ __forceinline__ unsigned short f2bf(float f) {
  unsigned int x = __float_as_uint(f);
  unsigned int r = (x + 0x7fffu + ((x >> 16) & 1u)) >> 16;  // RNE
  return (unsigned short)r;
}

// ---------- dtype detection (flags[0]=bf16 inputs, flags[1]=int64 indices) ----------
// R15 lesson: in_sizes are ELEMENT COUNTS (dtype-invariant) — host-side
// detection is impossible; this device probe is load-bearing.
__global__ void k_detect(const unsigned short* __restrict__ feat,
                         const unsigned int* __restrict__ eidx,
                         int* __restrict__ flags) {
  int lane = threadIdx.x;  // 64 threads
  float v = bf2f(feat[2 * lane]);
  bool big = !(fabsf(v) < 1000.0f);
  unsigned long long bb = __ballot(big);
  unsigned int w = eidx[2 * lane + 1];
  unsigned long long bz = __ballot(w == 0u);
  if (lane == 0) {
    flags[0] = (__popcll(bb) < 8) ? 1 : 0;
    flags[1] = (__popcll(bz) == 64) ? 1 : 0;
  }
}

__device__ __forceinline__ int eidx_at(const int* __restrict__ p, int k, int i64) {
  return p[i64 ? (k << 1) : k];
}

// ---------- one-time fragment prep (R12, verified) ----------
__global__ __launch_bounds__(256) void k_wprep(
    const void* __restrict__ W1, const void* __restrict__ A1s,
    const void* __restrict__ A1d, const void* __restrict__ W2,
    const void* __restrict__ A2s, const void* __restrict__ A2d,
    const int* __restrict__ flags, unsigned short* __restrict__ wfH,
    unsigned short* __restrict__ wfL, unsigned short* __restrict__ baf) {
  __shared__ float Wsh[DIM * DIM];
  __shared__ float was[DIM], wad[DIM];
  const int b = blockIdx.x;  // head-matrix 0..7
  const int t = threadIdx.x;
  const int bf = flags[0];
  const void* Wv = (b < 4) ? W1 : W2;
  const void* av = (b < 4) ? A1s : A2s;
  const void* dv = (b < 4) ? A1d : A2d;
  const int hm = (b < 4) ? b : b - 4;
  for (int i = t; i < DIM * DIM; i += 256)
    Wsh[i] = bf ? bf2f(((const unsigned short*)Wv)[hm * DIM * DIM + i])
                : ((const float*)Wv)[hm * DIM * DIM + i];
  __syncthreads();
  if (t < 128) {
    int k = t & 63, isd = t >> 6;
    const void* aptr = isd ? dv : av;
    float acc = 0.f;
    for (int c = 0; c < DIM; ++c) {
      float a = bf ? bf2f(((const unsigned short*)aptr)[hm * DIM + c])
                   : ((const float*)aptr)[hm * DIM + c];
      acc = fmaf(Wsh[k * DIM + c], a, acc);
    }
    (isd ? wad : was)[k] = acc;
  }
  __syncthreads();
  // W fragments: value at (cb,ks,lane,j) = W[(32ks+8g4+j)*64 + 16cb+r16]
  for (int idx = t; idx < 512; idx += 256) {
    int lane = idx & 63, ks = (idx >> 6) & 1, cb = idx >> 7;
    int g4 = lane >> 4, r16 = lane & 15;
    int fo = (((b * 4 + cb) * 2 + ks) * 64 + lane) * 8;
#pragma unroll
    for (int j = 0; j < 8; ++j) {
      int k = 32 * ks + 8 * g4 + j;
      float w = Wsh[k * DIM + 16 * cb + r16];
      unsigned short hu = f2bf(w);
      wfH[fo + j] = hu;
      wfL[fo + j] = f2bf(w - bf2f(hu));
    }
  }
  // score fragments
  for (int idx = t; idx < 128; idx += 256) {
    int lane = idx & 63, ks = idx >> 6;
    int g4 = lane >> 4, r16 = lane & 15;
    int fo = ((b * 2 + ks) * 64 + lane) * 8;
#pragma unroll
    for (int j = 0; j < 8; ++j) {
      int k = 32 * ks + 8 * g4 + j;
      unsigned short u = 0;
      if (r16 < 4) {
        float w_ = (r16 < 2) ? was[k] : wad[k];
        unsigned short uh = f2bf(w_);
        u = (r16 & 1) ? f2bf(w_ - bf2f(uh)) : uh;
      }
      baf[fo + j] = u;
    }
  }
}

// ---------- generalized scan (n <= 65536) ----------
__global__ void k_scan1(const int* __restrict__ in, int* __restrict__ out,
                        int* __restrict__ bsum, int n) {
  __shared__ int sm[256];
  int t = threadIdx.x, b = blockIdx.x, i = b * 256 + t;
  int v = (i < n) ? in[i] : 0;
  sm[t] = v;
  __syncthreads();
  for (int off = 1; off < 256; off <<= 1) {
    int x = (t >= off) ? sm[t - off] : 0;
    __syncthreads();
    sm[t] += x;
    __syncthreads();
  }
  if (i < n) out[i] = sm[t] - v;
  if (t == 255) bsum[b] = sm[t];
}

__global__ void k_scan2(int* __restrict__ bsum, int nb) {
  __shared__ int sm[256];
  int t = threadIdx.x;
  int v = (t < nb) ? bsum[t] : 0;
  sm[t] = v;
  __syncthreads();
  for (int off = 1; off < 256; off <<= 1) {
    int x = (t >= off) ? sm[t - off] : 0;
    __syncthreads();
    sm[t] += x;
    __syncthreads();
  }
  if (t < nb) bsum[t] = sm[t] - v;
}

__global__ void k_scan3(int* __restrict__ out, const int* __restrict__ bsum, int n) {
  int t = threadIdx.x, b = blockIdx.x, i = b * 256 + t;
  if (i < n) out[i] += bsum[b];
}

// ---------- bucketed CSR build ----------
__global__ __launch_bounds__(256) void k_hist1(const int* __restrict__ eidx,
                                               const int* __restrict__ flags,
                                               int* __restrict__ hist) {
  __shared__ int h[NB];
  int t = threadIdx.x, b = blockIdx.x;
  for (int i = t; i < NB; i += 256) h[i] = 0;
  __syncthreads();
  int i64 = flags[1];
  int lo = b * CHUNK;
  for (int i = t; i < CHUNK; i += 256) {
    int d = eidx_at(eidx, N_EDGES + lo + i, i64);
    atomicAdd(&h[d >> 7], 1);
  }
  __syncthreads();
  for (int i = t; i < NB; i += 256) hist[i * NBLK + b] = h[i];
}

__global__ __launch_bounds__(256) void k_scatter(const int* __restrict__ eidx,
                                                 const int* __restrict__ flags,
                                                 const int* __restrict__ hscan,
                                                 int2* __restrict__ ebuf) {
  __shared__ int cur[NB];
  int t = threadIdx.x, b = blockIdx.x;
  for (int i = t; i < NB; i += 256) cur[i] = hscan[i * NBLK + b];
  __syncthreads();
  int i64 = flags[1];
  int lo = b * CHUNK;
  for (int i = t; i < CHUNK; i += 256) {
    int d = eidx_at(eidx, N_EDGES + lo + i, i64);
    int s = eidx_at(eidx, lo + i, i64);
    int pos = atomicAdd(&cur[d >> 7], 1);
    ebuf[pos] = make_int2(s, d);
  }
}

__global__ __launch_bounds__(256) void k_place(const int2* __restrict__ ebuf,
                                               const int* __restrict__ hscan,
                                               int* __restrict__ rowp,
                                               int* __restrict__ csr) {
  __shared__ int hcnt[128];
  __shared__ int sm[128];
  __shared__ int cur[128];
  __shared__ int lcsr[CAP];
  int t = threadIdx.x, b = blockIdx.x;
  int lo = hscan[b * NBLK];
  int hi = (b + 1 < NB) ? hscan[(b + 1) * NBLK] : N_EDGES;
  if (t < 128) hcnt[t] = 0;
  __syncthreads();
  for (int i = lo + t; i < hi; i += 256) atomicAdd(&hcnt[ebuf[i].y & 127], 1);
  __syncthreads();
  int v = (t < 128) ? hcnt[t] : 0;
  if (t < 128) sm[t] = v;
  __syncthreads();
  for (int off = 1; off < 128; off <<= 1) {
    int x = (t < 128 && t >= off) ? sm[t - off] : 0;
    __syncthreads();
    if (t < 128) sm[t] += x;
    __syncthreads();
  }
  int d0 = b * 128;
  if (t < 128) {
    int excl = sm[t] - v;  // exclusive local prefix
    cur[t] = excl;
    int d = d0 + t;
    if (d < N_NODES) rowp[d] = lo + excl;
  }
  if (b == NB - 1 && t == 0) rowp[N_NODES] = N_EDGES;
  __syncthreads();
  int seg_sz = hi - lo;
  if (seg_sz <= CAP) {
    for (int i = lo + t; i < hi; i += 256) {
      int2 pr = ebuf[i];
      int pos = atomicAdd(&cur[pr.y & 127], 1);
      lcsr[pos] = pr.x;
    }
    __syncthreads();
    for (int i = t; i < seg_sz; i += 256) csr[lo + i] = lcsr[i];
  } else {  // overflow fallback
    for (int i = lo + t; i < hi; i += 256) {
      int2 pr = ebuf[i];
      int pos = atomicAdd(&cur[pr.y & 127], 1);
      csr[lo + pos] = pr.x;
    }
  }
}

// ---------- MFMA h = x@W, layer 0 only (direct feat read, in-register hi/lo) ----------
__global__ __launch_bounds__(256) void k_gemm(
    const void* __restrict__ xv,
    const unsigned short* __restrict__ wfH, const unsigned short* __restrict__ wfL,
    const unsigned short* __restrict__ baf, int mat,
    const int* __restrict__ flags, unsigned short* __restrict__ hb,
    float* __restrict__ ss, float* __restrict__ sd) {
  const int bf = flags[0];
  const int lane = threadIdx.x & 63;
  const int w = blockIdx.x * 4 + (threadIdx.x >> 6);
  const int wtile = w >> 1;
  if (wtile >= NTILES) return;
  const int cbh = (w & 1) * 2;  // col-blocks {cbh, cbh+1}
  const int r16 = lane & 15;
  const int g4 = lane >> 4;
  const int row0 = wtile * 16;

  const bf16x8* WH = (const bf16x8*)wfH;
  const bf16x8* WL = (const bf16x8*)wfL;
  bf16x8 Bh[2][2], Bl[2][2];
#pragma unroll
  for (int c = 0; c < 2; ++c)
#pragma unroll
    for (int ks = 0; ks < 2; ++ks) {
      int fi = ((mat * 4 + cbh + c) * 2 + ks) * 64 + lane;
      Bh[c][ks] = WH[fi];
      Bl[c][ks] = WL[fi];
    }

  bf16x8 Ah[2], Al[2];
  if (bf) {
    const unsigned short* xp = (const unsigned short*)xv + (row0 + r16) * DIM + 8 * g4;
#pragma unroll
    for (int ks = 0; ks < 2; ++ks) Ah[ks] = *(const bf16x8*)(xp + 32 * ks);
  } else {
    const float* xp = (const float*)xv + (row0 + r16) * DIM + 8 * g4;
#pragma unroll
    for (int ks = 0; ks < 2; ++ks) {
      float4 f0 = *(const float4*)(xp + 32 * ks);
      float4 f1 = *(const float4*)(xp + 32 * ks + 4);
      float v[8] = {f0.x, f0.y, f0.z, f0.w, f1.x, f1.y, f1.z, f1.w};
#pragma unroll
      for (int j = 0; j < 8; ++j) {
        unsigned short hu = f2bf(v[j]);
        Ah[ks][j] = (short)hu;
        Al[ks][j] = (short)f2bf(v[j] - bf2f(hu));
      }
    }
  }

  f32x4 acc[2];
#pragma unroll
  for (int c = 0; c < 2; ++c) {
    acc[c] = (f32x4){0.f, 0.f, 0.f, 0.f};
#pragma unroll
    for (int ks = 0; ks < 2; ++ks) {
      acc[c] = __builtin_amdgcn_mfma_f32_16x16x32_bf16(Ah[ks], Bh[c][ks], acc[c], 0, 0, 0);
      if (!bf)
        acc[c] = __builtin_amdgcn_mfma_f32_16x16x32_bf16(Al[ks], Bh[c][ks], acc[c], 0, 0, 0);
      acc[c] = __builtin_amdgcn_mfma_f32_16x16x32_bf16(Ah[ks], Bl[c][ks], acc[c], 0, 0, 0);
    }
  }

#pragma unroll
  for (int c = 0; c < 2; ++c)
#pragma unroll
    for (int reg = 0; reg < 4; ++reg)
      hb[(row0 + 4 * g4 + reg) * DIM + (cbh + c) * 16 + r16] = f2bf(acc[c][reg]);

  if (cbh == 0) {
    f32x4 acc2 = (f32x4){0.f, 0.f, 0.f, 0.f};
#pragma unroll
    for (int ks = 0; ks < 2; ++ks) {
      bf16x8 Ba = *(const bf16x8*)(baf + ((mat * 2 + ks) * 64 + lane) * 8);
      acc2 = __builtin_amdgcn_mfma_f32_16x16x32_bf16(Ah[ks], Ba, acc2, 0, 0, 0);
      if (!bf)
        acc2 = __builtin_amdgcn_mfma_f32_16x16x32_bf16(Al[ks], Ba, acc2, 0, 0, 0);
    }
#pragma unroll
    for (int reg = 0; reg < 4; ++reg) {
      float tmp = acc2[reg] + __shfl_xor(acc2[reg], 1);  // col pairs (0,1)/(2,3)
      int row = row0 + 4 * g4 + reg;
      if (r16 == 0) ss[row] = tmp;
      else if (r16 == 2) sd[row] = tmp;
    }
  }
}

// ---------- shared agg pieces (R5-verified) ----------
__device__ __forceinline__ void quad_accum(const unsigned short* __restrict__ hb,
                                           const int2* __restrict__ lps, int cl,
                                           int quarter, int c16, float4& acc) {
  const int quads = (cl + 3) >> 2;
#pragma unroll 4
  for (int tt = 0; tt < quads; ++tt) {
    int j = 4 * tt + quarter;  // tail entries have p=0,s=0 -> contribute 0
    int2 pv = lps[j];          // LDS broadcast within quarter-wave
    float pj = __int_as_float(pv.x);
    int sj = pv.y;
    ushort4 hv = *(const ushort4*)(hb + sj * DIM + 4 * c16);
    acc.x = fmaf(pj, bf2f(hv.x), acc.x);
    acc.y = fmaf(pj, bf2f(hv.y), acc.y);
    acc.z = fmaf(pj, bf2f(hv.z), acc.z);
    acc.w = fmaf(pj, bf2f(hv.w), acc.w);
  }
}

__device__ __forceinline__ void agg_node_big(
    const unsigned short* __restrict__ hb, const float* __restrict__ ss,
    float sdn, int base, int deg, const int* __restrict__ csr, int lane,
    int quarter, int c16, int2* __restrict__ lpw, float4& acc, float& zo) {
  float z = 0.f;
  for (int c = 0; c < deg; c += 64) {
    int j = c + lane;
    float p = 0.f; int s = 0;
    if (j < deg) {
      s = csr[base + j];
      float sc = ss[s] + sdn;
      sc = (sc >= 0.f) ? sc : 0.2f * sc;
      p = __expf(sc);
    }
    lpw[lane] = make_int2(__float_as_int(p), s);
    __builtin_amdgcn_wave_barrier();
    z += p;
    const int cl = (deg - c < 64) ? (deg - c) : 64;
    quad_accum(hb, lpw, cl, quarter, c16, acc);
    __builtin_amdgcn_wave_barrier();
  }
#pragma unroll
  for (int off = 32; off > 0; off >>= 1) z += __shfl_xor(z, off);
  zo = z;
}

// computes softmax-weighted aggregate for `node` into (ox..ow) on all lanes
// (lane's c16 selects cols 4c16..4c16+3). elu applied if do_elu.
__device__ __forceinline__ void agg_core(
    const unsigned short* __restrict__ hb, const float* __restrict__ ss,
    const float* __restrict__ sd, const int* __restrict__ rowp,
    const int* __restrict__ csr, int node, int lane, int quarter, int c16,
    int do_elu, int2* __restrict__ lpw, float& ox, float& oy, float& oz,
    float& ow) {
  const int base = rowp[node];
  const int deg = rowp[node + 1] - base;
  const float sdn = sd[node];
  float4 acc = {0.f, 0.f, 0.f, 0.f};
  float z;
  if (deg <= 64) {
    int s = 0;
    float p = 0.f;
    if (lane < deg) {
      s = csr[base + lane];
      float t = ss[s] + sdn;
      t = (t >= 0.f) ? t : 0.2f * t;
      p = __expf(t);  // shift-invariant softmax, scores O(10)
    }
    lpw[lane] = make_int2(__float_as_int(p), s);
    z = p;
    __builtin_amdgcn_wave_barrier();
    quad_accum(hb, lpw, deg, quarter, c16, acc);
    __builtin_amdgcn_wave_barrier();  // lpw reused by caller's next node
#pragma unroll
    for (int off = 32; off > 0; off >>= 1) z += __shfl_xor(z, off);
  } else {
    agg_node_big(hb, ss, sdn, base, deg, csr, lane, quarter, c16, lpw, acc, z);
  }
  acc.x += __shfl_xor(acc.x, 16);
  acc.y += __shfl_xor(acc.y, 16);
  acc.z += __shfl_xor(acc.z, 16);
  acc.w += __shfl_xor(acc.w, 16);
  acc.x += __shfl_xor(acc.x, 32);
  acc.y += __shfl_xor(acc.y, 32);
  acc.z += __shfl_xor(acc.z, 32);
  acc.w += __shfl_xor(acc.w, 32);
  float inv = 1.f / (z + 1e-16f);
  ox = acc.x * inv; oy = acc.y * inv;
  oz = acc.z * inv; ow = acc.w * inv;
  if (do_elu) {
    ox = (ox > 0.f) ? ox : expm1f(ox);
    oy = (oy > 0.f) ? oy : expm1f(oy);
    oz = (oz > 0.f) ? oz : expm1f(oz);
    ow = (ow > 0.f) ? ow : expm1f(ow);
  }
}

// ---------- fused agg->gemm (R12-measured best: batched phase-1 + serial
// per-node gather loops, plain launch_bounds(512); 347.9us total verified) ----------
__global__ __launch_bounds__(512) void k_fused(
    const unsigned short* __restrict__ hb_in, const float* __restrict__ ss_in,
    const float* __restrict__ sd_in, const int* __restrict__ rowp,
    const int* __restrict__ csr, const unsigned short* __restrict__ wfH,
    const unsigned short* __restrict__ wfL, const unsigned short* __restrict__ baf,
    int mat, int do_elu, unsigned short* __restrict__ hb_out,
    float* __restrict__ ss_out, float* __restrict__ sd_out) {
  __shared__ float outT[FROWS][FPAD];
  __shared__ __align__(16) int2 lps[8][4][64];  // per wave: 4 node buffers (16 KB)
  const int tid = threadIdx.x;
  const int lane = tid & 63;
  const int w = tid >> 6;  // 0..7
  const int quarter = lane >> 4;
  const int c16 = lane & 15;
  const int blk = blockIdx.x;
  const int node0 = blk * FROWS + w * 4;

  // wave-uniform row pointers (clamped: OOB nodes get deg 0)
  int bp[5];
#pragma unroll
  for (int j = 0; j < 5; ++j) {
    int idx = node0 + j;
    bp[j] = rowp[(idx < N_NODES) ? idx : N_NODES];
  }
  int deg[4];
  float sdn[4];
#pragma unroll
  for (int j = 0; j < 4; ++j) {
    deg[j] = bp[j + 1] - bp[j];
    int idx = node0 + j;
    sdn[j] = sd_in[(idx < N_NODES) ? idx : (N_NODES - 1)];
  }

  if (deg[0] <= 64 && deg[1] <= 64 && deg[2] <= 64 && deg[3] <= 64) {
    // ---- batched phase 1: 4 independent csr loads, then 4 independent ss gathers
    int s4[4];
    float p4[4];
#pragma unroll
    for (int j = 0; j < 4; ++j)
      s4[j] = (lane < deg[j]) ? csr[bp[j] + lane] : 0;
#pragma unroll
    for (int j = 0; j < 4; ++j) {
      float t = ss_in[s4[j]] + sdn[j];
      t = (t >= 0.f) ? t : 0.2f * t;
      p4[j] = (lane < deg[j]) ? __expf(t) : 0.f;
    }
#pragma unroll
    for (int j = 0; j < 4; ++j)
      lps[w][j][lane] = make_int2(__float_as_int(p4[j]), s4[j]);
    __builtin_amdgcn_wave_barrier();

    // ---- 4 gather loops (serial per node; compiler pipelines within each)
    float4 acc[4];
#pragma unroll
    for (int j = 0; j < 4; ++j) acc[j] = (float4){0.f, 0.f, 0.f, 0.f};
#pragma unroll
    for (int j = 0; j < 4; ++j)
      quad_accum(hb_in, &lps[w][j][0], deg[j], quarter, c16, acc[j]);

    // ---- z reductions + epilogues
#pragma unroll
    for (int j = 0; j < 4; ++j) {
      float z = p4[j];
#pragma unroll
      for (int off = 32; off > 0; off >>= 1) z += __shfl_xor(z, off);
      float4 a = acc[j];
      a.x += __shfl_xor(a.x, 16);
      a.y += __shfl_xor(a.y, 16);
      a.z += __shfl_xor(a.z, 16);
      a.w += __shfl_xor(a.w, 16);
      a.x += __shfl_xor(a.x, 32);
      a.y += __shfl_xor(a.y, 32);
      a.z += __shfl_xor(a.z, 32);
      a.w += __shfl_xor(a.w, 32);
      float inv = 1.f / (z + 1e-16f);
      float ox = a.x * inv, oy = a.y * inv, oz = a.z * inv, ow = a.w * inv;
      if (do_elu) {
        ox = (ox > 0.f) ? ox : expm1f(ox);
        oy = (oy > 0.f) ? oy : expm1f(oy);
        oz = (oz > 0.f) ? oz : expm1f(oz);
        ow = (ow > 0.f) ? ow : expm1f(ow);
      }
      if (quarter == 0) {
        float4 o4 = {ox, oy, oz, ow};
        *(float4*)&outT[w * 4 + j][4 * c16] = o4;  // 16B-aligned
      }
    }
  } else {
    // rare path: verified per-node serial agg
    for (int j = 0; j < 4; ++j) {
      const int row = w * 4 + j;
      const int node = node0 + j;
      float ox = 0.f, oy = 0.f, oz = 0.f, ow = 0.f;
      if (node < N_NODES)
        agg_core(hb_in, ss_in, sd_in, rowp, csr, node, lane, quarter, c16,
                 do_elu, &lps[w][j][0], ox, oy, oz, ow);
      if (quarter == 0) {
        float4 o4 = {ox, oy, oz, ow};
        *(float4*)&outT[row][4 * c16] = o4;
      }
    }
  }
  __syncthreads();

  // ---- gemm phase: wave w -> tile t=w>>2 (rows t*16..+15), cb=w&3 ----
  const int t = w >> 2;
  const int cb = w & 3;
  const int r16 = c16;
  const int g4 = quarter;

  bf16x8 Ah[2], Al[2];
#pragma unroll
  for (int ks = 0; ks < 2; ++ks) {
    const float* src = &outT[t * 16 + r16][32 * ks + 8 * g4];
    float4 f0 = *(const float4*)src;
    float4 f1 = *(const float4*)(src + 4);
    float v[8] = {f0.x, f0.y, f0.z, f0.w, f1.x, f1.y, f1.z, f1.w};
#pragma unroll
    for (int jj = 0; jj < 8; ++jj) {
      unsigned short hu = f2bf(v[jj]);
      Ah[ks][jj] = (short)hu;
      Al[ks][jj] = (short)f2bf(v[jj] - bf2f(hu));
    }
  }

  const bf16x8* WH = (const bf16x8*)wfH;
  const bf16x8* WL = (const bf16x8*)wfL;
  f32x4 acc2 = (f32x4){0.f, 0.f, 0.f, 0.f};
#pragma unroll
  for (int ks = 0; ks < 2; ++ks) {
    int fi = ((mat * 4 + cb) * 2 + ks) * 64 + lane;
    bf16x8 Bh = WH[fi];
    bf16x8 Bl = WL[fi];
    acc2 = __builtin_amdgcn_mfma_f32_16x16x32_bf16(Ah[ks], Bh, acc2, 0, 0, 0);
    acc2 = __builtin_amdgcn_mfma_f32_16x16x32_bf16(Al[ks], Bh, acc2, 0, 0, 0);
    acc2 = __builtin_amdgcn_mfma_f32_16x16x32_bf16(Ah[ks], Bl, acc2, 0, 0, 0);
  }
#pragma unroll
  for (int reg = 0; reg < 4; ++reg) {
    int row = blk * FROWS + t * 16 + 4 * g4 + reg;
    if (row < N_NODES) hb_out[row * DIM + cb * 16 + r16] = f2bf(acc2[reg]);
  }

  if (cb == 0) {
    f32x4 accs = (f32x4){0.f, 0.f, 0.f, 0.f};
#pragma unroll
    for (int ks = 0; ks < 2; ++ks) {
      bf16x8 Ba = *(const bf16x8*)(baf + ((mat * 2 + ks) * 64 + lane) * 8);
      accs = __builtin_amdgcn_mfma_f32_16x16x32_bf16(Ah[ks], Ba, accs, 0, 0, 0);
      accs = __builtin_amdgcn_mfma_f32_16x16x32_bf16(Al[ks], Ba, accs, 0, 0, 0);
    }
#pragma unroll
    for (int reg = 0; reg < 4; ++reg) {
      float tmp = accs[reg] + __shfl_xor(accs[reg], 1);  // col pairs
      int row = blk * FROWS + t * 16 + 4 * g4 + reg;
      if (row < N_NODES) {
        if (r16 == 0) ss_out[row] = tmp;
        else if (r16 == 2) sd_out[row] = tmp;
      }
    }
  }
}

// ---------- final-layer agg (R5-verified single-node; is_final path) ----------
__global__ __launch_bounds__(256) void k_agg(
    const unsigned short* __restrict__ hb, const float* __restrict__ ss,
    const float* __restrict__ sd, const int* __restrict__ rowp,
    const int* __restrict__ csr, void* __restrict__ out_final,
    const int* __restrict__ flags, int do_elu) {
  __shared__ __align__(16) int2 lps[4][64];
  const int lane = threadIdx.x & 63;
  const int quarter = lane >> 4;
  const int c16 = lane & 15;
  const int w = threadIdx.x >> 6;
  const int node = blockIdx.x * 4 + w;
  float ox, oy, oz, ow;
  agg_core(hb, ss, sd, rowp, csr, node, lane, quarter, c16, do_elu,
           &lps[w][0], ox, oy, oz, ow);
  if (quarter == 0) {
    int idx = node * DIM + 4 * c16;
    if (flags[0]) {
      ushort4 o4 = {f2bf(ox), f2bf(oy), f2bf(oz), f2bf(ow)};
      *(ushort4*)((unsigned short*)out_final + idx) = o4;
    } else {
      float4 o4 = {ox, oy, oz, ow};
      *(float4*)((float*)out_final + idx) = o4;
    }
  }
}

// ---------- launch ----------
extern "C" void kernel_launch(void* const* d_in, const int* in_sizes, int n_in,
                              void* d_out, int out_size, void* d_ws, size_t ws_size,
                              hipStream_t stream) {
  const void* feat = d_in[0];
  const int* eidx = (const int*)d_in[1];

  unsigned short* hbA = (unsigned short*)d_ws;          // N*64 bf16
  unsigned short* hbB = hbA + N_NODES * DIM;            // N*64 bf16
  unsigned short* wfH = hbB + N_NODES * DIM;            // 32768
  unsigned short* wfL = wfH + 32768;                    // 32768
  unsigned short* baf = wfL + 32768;                    // 8192
  int2* ebuf = (int2*)(baf + 8192);                     // E int2
  float* ssA = (float*)(ebuf + N_EDGES);                // N
  float* sdA = ssA + N_NODES;                           // N
  float* ssB = sdA + N_NODES;                           // N
  float* sdB = ssB + N_NODES;                           // N
  int* csr  = (int*)(sdB + N_NODES);                    // E
  int* hist = csr + N_EDGES;                            // NB*NBLK
  int* hscan = hist + NB * NBLK;                        // NB*NBLK
  int* bsum = hscan + NB * NBLK;                        // 256
  int* rowp = bsum + 256;                               // N+1
  int* flags = rowp + N_NODES + 1;                      // 2

  const int NH = NB * NBLK;                 // 50048
  const int SBH = (NH + 255) / 256;         // 196

  k_detect<<<1, 64, 0, stream>>>((const unsigned short*)feat,
                                 (const unsigned int*)eidx, flags);
  k_wprep<<<8, 256, 0, stream>>>(d_in[2], d_in[3], d_in[4],
                                 d_in[5], d_in[6], d_in[7],
                                 flags, wfH, wfL, baf);
  k_hist1<<<NBLK, 256, 0, stream>>>(eidx, flags, hist);
  k_scan1<<<SBH, 256, 0, stream>>>(hist, hscan, bsum, NH);
  k_scan2<<<1, 256, 0, stream>>>(bsum, SBH);
  k_scan3<<<SBH, 256, 0, stream>>>(hscan, bsum, NH);
  k_scatter<<<NBLK, 256, 0, stream>>>(eidx, flags, hscan, ebuf);
  k_place<<<NB, 256, 0, stream>>>(ebuf, hscan, rowp, csr);

  const int GB = (2 * NTILES + 3) / 4;              // layer-0 gemm
  const int FB = (N_NODES + FROWS - 1) / FROWS;     // 1563 fused blocks

  // layer 0 gemm: features -> hbA, ssA, sdA (direct feat read)
  k_gemm<<<GB, 256, 0, stream>>>(feat, wfH, wfL, baf, 0, flags, hbA, ssA, sdA);

  // 7 fused layers: agg(k) + gemm(k+1). X_0 = A; alternate.
  for (int k = 0; k < 7; ++k) {
    const unsigned short* hin = (k & 1) ? hbB : hbA;
    const float* sin_ = (k & 1) ? ssB : ssA;
    const float* din = (k & 1) ? sdB : sdA;
    unsigned short* hout = (k & 1) ? hbA : hbB;
    float* sout = (k & 1) ? ssA : ssB;
    float* dout = (k & 1) ? sdA : sdB;
    k_fused<<<FB, 512, 0, stream>>>(hin, sin_, din, rowp, csr, wfH, wfL, baf,
                                    k + 1, (k == 3) ? 1 : 0, hout, sout, dout);
  }

  // final agg (layer 7): X_7 = B (7 fused flips from A)
  k_agg<<<N_NODES / 4, 256, 0, stream>>>(hbB, ssB, sdB, rowp, csr, d_out,
                                         flags, 1);
}

// Round 23
// 346.886 us; speedup vs baseline: 1.1154x; 1.0065x over previous
//
#include <hip/hip_runtime.h>
#include <hip/hip_bf16.h>

#define N_NODES 50000
#define N_EDGES 800000
#define DIM 64
#define NB 391      // dst buckets of 128 nodes: ceil(50000/128)
#define NBLK 128    // blocks in bucketize pass
#define CHUNK 6250  // N_EDGES / NBLK (exact)
#define CAP 4096    // LDS staging capacity per bucket segment (avg ~2048)
#define NTILES 3125 // 50000 / 16 row-tiles (exact)
#define FROWS 32    // fused kernel: rows (nodes) per block
#define FPAD 68     // LDS row stride (floats): 16B-aligned, 68%32=4 -> 2-way banks

typedef __attribute__((ext_vector_type(8))) short bf16x8;
typedef __attribute__((ext_vector_type(4))) float f32x4;

// ---------- helpers ----------
__device__ __forceinline__ float bf2f(unsigned short u) {
  return __uint_as_float(((unsigned int)u) << 16);
}
__device__ __forceinline__ unsigned short f2bf(float f) {
  unsigned int x = __float_as_uint(f);
  unsigned int r = (x + 0x7fffu + ((x >> 16) & 1u)) >> 16;  // RNE
  return (unsigned short)r;
}

__device__ __forceinline__ int eidx_at(const int* __restrict__ p, int k, int i64) {
  return p[i64 ? (k << 1) : k];
}

// ---------- fragment prep + INLINE dtype detection (R22: k_detect folded in) ----------
// Each block recomputes the dtype probe in wave 0 (64 loads + 2 ballots,
// redundant but trivial); block 0 publishes flags[] for downstream kernels.
// R15 lesson: in_sizes are ELEMENT COUNTS — detection must be on-device.
__global__ __launch_bounds__(256) void k_wprep(
    const void* __restrict__ W1, const void* __restrict__ A1s,
    const void* __restrict__ A1d, const void* __restrict__ W2,
    const void* __restrict__ A2s, const void* __restrict__ A2d,
    const unsigned short* __restrict__ feat, const unsigned int* __restrict__ eidx,
    int* __restrict__ flags, unsigned short* __restrict__ wfH,
    unsigned short* __restrict__ wfL, unsigned short* __restrict__ baf) {
  __shared__ float Wsh[DIM * DIM];
  __shared__ float was[DIM], wad[DIM];
  __shared__ int sbf;
  const int b = blockIdx.x;  // head-matrix 0..7
  const int t = threadIdx.x;
  if (t < 64) {  // wave 0: dtype probe (same logic as the old k_detect)
    float v = bf2f(feat[2 * t]);
    bool big = !(fabsf(v) < 1000.0f);
    unsigned long long bb = __ballot(big);
    unsigned int wv = eidx[2 * t + 1];
    unsigned long long bz = __ballot(wv == 0u);
    if (t == 0) {
      int bfv = (__popcll(bb) < 8) ? 1 : 0;
      int i64v = (__popcll(bz) == 64) ? 1 : 0;
      sbf = bfv;
      if (b == 0) { flags[0] = bfv; flags[1] = i64v; }
    }
  }
  __syncthreads();
  const int bf = sbf;
  const void* Wv = (b < 4) ? W1 : W2;
  const void* av = (b < 4) ? A1s : A2s;
  const void* dv = (b < 4) ? A1d : A2d;
  const int hm = (b < 4) ? b : b - 4;
  for (int i = t; i < DIM * DIM; i += 256)
    Wsh[i] = bf ? bf2f(((const unsigned short*)Wv)[hm * DIM * DIM + i])
                : ((const float*)Wv)[hm * DIM * DIM + i];
  __syncthreads();
  if (t < 128) {
    int k = t & 63, isd = t >> 6;
    const void* aptr = isd ? dv : av;
    float acc = 0.f;
    for (int c = 0; c < DIM; ++c) {
      float a = bf ? bf2f(((const unsigned short*)aptr)[hm * DIM + c])
                   : ((const float*)aptr)[hm * DIM + c];
      acc = fmaf(Wsh[k * DIM + c], a, acc);
    }
    (isd ? wad : was)[k] = acc;
  }
  __syncthreads();
  // W fragments: value at (cb,ks,lane,j) = W[(32ks+8g4+j)*64 + 16cb+r16]
  for (int idx = t; idx < 512; idx += 256) {
    int lane = idx & 63, ks = (idx >> 6) & 1, cb = idx >> 7;
    int g4 = lane >> 4, r16 = lane & 15;
    int fo = (((b * 4 + cb) * 2 + ks) * 64 + lane) * 8;
#pragma unroll
    for (int j = 0; j < 8; ++j) {
      int k = 32 * ks + 8 * g4 + j;
      float w = Wsh[k * DIM + 16 * cb + r16];
      unsigned short hu = f2bf(w);
      wfH[fo + j] = hu;
      wfL[fo + j] = f2bf(w - bf2f(hu));
    }
  }
  // score fragments
  for (int idx = t; idx < 128; idx += 256) {
    int lane = idx & 63, ks = idx >> 6;
    int g4 = lane >> 4, r16 = lane & 15;
    int fo = ((b * 2 + ks) * 64 + lane) * 8;
#pragma unroll
    for (int j = 0; j < 8; ++j) {
      int k = 32 * ks + 8 * g4 + j;
      unsigned short u = 0;
      if (r16 < 4) {
        float w_ = (r16 < 2) ? was[k] : wad[k];
        unsigned short uh = f2bf(w_);
        u = (r16 & 1) ? f2bf(w_ - bf2f(uh)) : uh;
      }
      baf[fo + j] = u;
    }
  }
}

// ---------- scan (R22: 2 kernels — scan2 folded into scan3) ----------
__global__ void k_scan1(const int* __restrict__ in, int* __restrict__ out,
                        int* __restrict__ bsum, int n) {
  __shared__ int sm[256];
  int t = threadIdx.x, b = blockIdx.x, i = b * 256 + t;
  int v = (i < n) ? in[i] : 0;
  sm[t] = v;
  __syncthreads();
  for (int off = 1; off < 256; off <<= 1) {
    int x = (t >= off) ? sm[t - off] : 0;
    __syncthreads();
    sm[t] += x;
    __syncthreads();
  }
  if (i < n) out[i] = sm[t] - v;
  if (t == 255) bsum[b] = sm[t];  // raw per-block total (no scan2 pass now)
}

// adds the exclusive prefix of bsum[0..b) to this block's outputs; the
// prefix is computed per-block via a 256-wide tree reduce (nb <= 256).
__global__ void k_scan3(int* __restrict__ out, const int* __restrict__ bsum, int n) {
  __shared__ int sm[256];
  int t = threadIdx.x, b = blockIdx.x;
  sm[t] = (t < b) ? bsum[t] : 0;  // b <= 195 < 256
  __syncthreads();
  for (int off = 128; off > 0; off >>= 1) {
    if (t < off) sm[t] += sm[t + off];
    __syncthreads();
  }
  int offset = sm[0];
  int i = b * 256 + t;
  if (i < n) out[i] += offset;
}

// ---------- bucketed CSR build ----------
__global__ __launch_bounds__(256) void k_hist1(const int* __restrict__ eidx,
                                               const int* __restrict__ flags,
                                               int* __restrict__ hist) {
  __shared__ int h[NB];
  int t = threadIdx.x, b = blockIdx.x;
  for (int i = t; i < NB; i += 256) h[i] = 0;
  __syncthreads();
  int i64 = flags[1];
  int lo = b * CHUNK;
  for (int i = t; i < CHUNK; i += 256) {
    int d = eidx_at(eidx, N_EDGES + lo + i, i64);
    atomicAdd(&h[d >> 7], 1);
  }
  __syncthreads();
  for (int i = t; i < NB; i += 256) hist[i * NBLK + b] = h[i];
}

__global__ __launch_bounds__(256) void k_scatter(const int* __restrict__ eidx,
                                                 const int* __restrict__ flags,
                                                 const int* __restrict__ hscan,
                                                 int2* __restrict__ ebuf) {
  __shared__ int cur[NB];
  int t = threadIdx.x, b = blockIdx.x;
  for (int i = t; i < NB; i += 256) cur[i] = hscan[i * NBLK + b];
  __syncthreads();
  int i64 = flags[1];
  int lo = b * CHUNK;
  for (int i = t; i < CHUNK; i += 256) {
    int d = eidx_at(eidx, N_EDGES + lo + i, i64);
    int s = eidx_at(eidx, lo + i, i64);
    int pos = atomicAdd(&cur[d >> 7], 1);
    ebuf[pos] = make_int2(s, d);
  }
}

__global__ __launch_bounds__(256) void k_place(const int2* __restrict__ ebuf,
                                               const int* __restrict__ hscan,
                                               int* __restrict__ rowp,
                                               int* __restrict__ csr) {
  __shared__ int hcnt[128];
  __shared__ int sm[128];
  __shared__ int cur[128];
  __shared__ int lcsr[CAP];
  int t = threadIdx.x, b = blockIdx.x;
  int lo = hscan[b * NBLK];
  int hi = (b + 1 < NB) ? hscan[(b + 1) * NBLK] : N_EDGES;
  if (t < 128) hcnt[t] = 0;
  __syncthreads();
  for (int i = lo + t; i < hi; i += 256) atomicAdd(&hcnt[ebuf[i].y & 127], 1);
  __syncthreads();
  int v = (t < 128) ? hcnt[t] : 0;
  if (t < 128) sm[t] = v;
  __syncthreads();
  for (int off = 1; off < 128; off <<= 1) {
    int x = (t < 128 && t >= off) ? sm[t - off] : 0;
    __syncthreads();
    if (t < 128) sm[t] += x;
    __syncthreads();
  }
  int d0 = b * 128;
  if (t < 128) {
    int excl = sm[t] - v;  // exclusive local prefix
    cur[t] = excl;
    int d = d0 + t;
    if (d < N_NODES) rowp[d] = lo + excl;
  }
  if (b == NB - 1 && t == 0) rowp[N_NODES] = N_EDGES;
  __syncthreads();
  int seg_sz = hi - lo;
  if (seg_sz <= CAP) {
    for (int i = lo + t; i < hi; i += 256) {
      int2 pr = ebuf[i];
      int pos = atomicAdd(&cur[pr.y & 127], 1);
      lcsr[pos] = pr.x;
    }
    __syncthreads();
    for (int i = t; i < seg_sz; i += 256) csr[lo + i] = lcsr[i];
  } else {  // overflow fallback
    for (int i = lo + t; i < hi; i += 256) {
      int2 pr = ebuf[i];
      int pos = atomicAdd(&cur[pr.y & 127], 1);
      csr[lo + pos] = pr.x;
    }
  }
}

// ---------- MFMA h = x@W, layer 0 only (direct feat read, in-register hi/lo) ----------
__global__ __launch_bounds__(256) void k_gemm(
    const void* __restrict__ xv,
    const unsigned short* __restrict__ wfH, const unsigned short* __restrict__ wfL,
    const unsigned short* __restrict__ baf, int mat,
    const int* __restrict__ flags, unsigned short* __restrict__ hb,
    float* __restrict__ ss, float* __restrict__ sd) {
  const int bf = flags[0];
  const int lane = threadIdx.x & 63;
  const int w = blockIdx.x * 4 + (threadIdx.x >> 6);
  const int wtile = w >> 1;
  if (wtile >= NTILES) return;
  const int cbh = (w & 1) * 2;  // col-blocks {cbh, cbh+1}
  const int r16 = lane & 15;
  const int g4 = lane >> 4;
  const int row0 = wtile * 16;

  const bf16x8* WH = (const bf16x8*)wfH;
  const bf16x8* WL = (const bf16x8*)wfL;
  bf16x8 Bh[2][2], Bl[2][2];
#pragma unroll
  for (int c = 0; c < 2; ++c)
#pragma unroll
    for (int ks = 0; ks < 2; ++ks) {
      int fi = ((mat * 4 + cbh + c) * 2 + ks) * 64 + lane;
      Bh[c][ks] = WH[fi];
      Bl[c][ks] = WL[fi];
    }

  bf16x8 Ah[2], Al[2];
  if (bf) {
    const unsigned short* xp = (const unsigned short*)xv + (row0 + r16) * DIM + 8 * g4;
#pragma unroll
    for (int ks = 0; ks < 2; ++ks) Ah[ks] = *(const bf16x8*)(xp + 32 * ks);
  } else {
    const float* xp = (const float*)xv + (row0 + r16) * DIM + 8 * g4;
#pragma unroll
    for (int ks = 0; ks < 2; ++ks) {
      float4 f0 = *(const float4*)(xp + 32 * ks);
      float4 f1 = *(const float4*)(xp + 32 * ks + 4);
      float v[8] = {f0.x, f0.y, f0.z, f0.w, f1.x, f1.y, f1.z, f1.w};
#pragma unroll
      for (int j = 0; j < 8; ++j) {
        unsigned short hu = f2bf(v[j]);
        Ah[ks][j] = (short)hu;
        Al[ks][j] = (short)f2bf(v[j] - bf2f(hu));
      }
    }
  }

  f32x4 acc[2];
#pragma unroll
  for (int c = 0; c < 2; ++c) {
    acc[c] = (f32x4){0.f, 0.f, 0.f, 0.f};
#pragma unroll
    for (int ks = 0; ks < 2; ++ks) {
      acc[c] = __builtin_amdgcn_mfma_f32_16x16x32_bf16(Ah[ks], Bh[c][ks], acc[c], 0, 0, 0);
      if (!bf)
        acc[c] = __builtin_amdgcn_mfma_f32_16x16x32_bf16(Al[ks], Bh[c][ks], acc[c], 0, 0, 0);
      acc[c] = __builtin_amdgcn_mfma_f32_16x16x32_bf16(Ah[ks], Bl[c][ks], acc[c], 0, 0, 0);
    }
  }

#pragma unroll
  for (int c = 0; c < 2; ++c)
#pragma unroll
    for (int reg = 0; reg < 4; ++reg)
      hb[(row0 + 4 * g4 + reg) * DIM + (cbh + c) * 16 + r16] = f2bf(acc[c][reg]);

  if (cbh == 0) {
    f32x4 acc2 = (f32x4){0.f, 0.f, 0.f, 0.f};
#pragma unroll
    for (int ks = 0; ks < 2; ++ks) {
      bf16x8 Ba = *(const bf16x8*)(baf + ((mat * 2 + ks) * 64 + lane) * 8);
      acc2 = __builtin_amdgcn_mfma_f32_16x16x32_bf16(Ah[ks], Ba, acc2, 0, 0, 0);
      if (!bf)
        acc2 = __builtin_amdgcn_mfma_f32_16x16x32_bf16(Al[ks], Ba, acc2, 0, 0, 0);
    }
#pragma unroll
    for (int reg = 0; reg < 4; ++reg) {
      float tmp = acc2[reg] + __shfl_xor(acc2[reg], 1);  // col pairs (0,1)/(2,3)
      int row = row0 + 4 * g4 + reg;
      if (r16 == 0) ss[row] = tmp;
      else if (r16 == 2) sd[row] = tmp;
    }
  }
}

// ---------- shared agg pieces (R5-verified) ----------
__device__ __forceinline__ void quad_accum(const unsigned short* __restrict__ hb,
                                           const int2* __restrict__ lps, int cl,
                                           int quarter, int c16, float4& acc) {
  const int quads = (cl + 3) >> 2;
#pragma unroll 4
  for (int tt = 0; tt < quads; ++tt) {
    int j = 4 * tt + quarter;  // tail entries have p=0,s=0 -> contribute 0
    int2 pv = lps[j];          // LDS broadcast within quarter-wave
    float pj = __int_as_float(pv.x);
    int sj = pv.y;
    ushort4 hv = *(const ushort4*)(hb + sj * DIM + 4 * c16);
    acc.x = fmaf(pj, bf2f(hv.x), acc.x);
    acc.y = fmaf(pj, bf2f(hv.y), acc.y);
    acc.z = fmaf(pj, bf2f(hv.z), acc.z);
    acc.w = fmaf(pj, bf2f(hv.w), acc.w);
  }
}

__device__ __forceinline__ void agg_node_big(
    const unsigned short* __restrict__ hb, const float* __restrict__ ss,
    float sdn, int base, int deg, const int* __restrict__ csr, int lane,
    int quarter, int c16, int2* __restrict__ lpw, float4& acc, float& zo) {
  float z = 0.f;
  for (int c = 0; c < deg; c += 64) {
    int j = c + lane;
    float p = 0.f; int s = 0;
    if (j < deg) {
      s = csr[base + j];
      float sc = ss[s] + sdn;
      sc = (sc >= 0.f) ? sc : 0.2f * sc;
      p = __expf(sc);
    }
    lpw[lane] = make_int2(__float_as_int(p), s);
    __builtin_amdgcn_wave_barrier();
    z += p;
    const int cl = (deg - c < 64) ? (deg - c) : 64;
    quad_accum(hb, lpw, cl, quarter, c16, acc);
    __builtin_amdgcn_wave_barrier();
  }
#pragma unroll
  for (int off = 32; off > 0; off >>= 1) z += __shfl_xor(z, off);
  zo = z;
}

// computes softmax-weighted aggregate for `node` into (ox..ow) on all lanes
// (lane's c16 selects cols 4c16..4c16+3). elu applied if do_elu.
__device__ __forceinline__ void agg_core(
    const unsigned short* __restrict__ hb, const float* __restrict__ ss,
    const float* __restrict__ sd, const int* __restrict__ rowp,
    const int* __restrict__ csr, int node, int lane, int quarter, int c16,
    int do_elu, int2* __restrict__ lpw, float& ox, float& oy, float& oz,
    float& ow) {
  const int base = rowp[node];
  const int deg = rowp[node + 1] - base;
  const float sdn = sd[node];
  float4 acc = {0.f, 0.f, 0.f, 0.f};
  float z;
  if (deg <= 64) {
    int s = 0;
    float p = 0.f;
    if (lane < deg) {
      s = csr[base + lane];
      float t = ss[s] + sdn;
      t = (t >= 0.f) ? t : 0.2f * t;
      p = __expf(t);  // shift-invariant softmax, scores O(10)
    }
    lpw[lane] = make_int2(__float_as_int(p), s);
    z = p;
    __builtin_amdgcn_wave_barrier();
    quad_accum(hb, lpw, deg, quarter, c16, acc);
    __builtin_amdgcn_wave_barrier();  // lpw reused by caller's next node
#pragma unroll
    for (int off = 32; off > 0; off >>= 1) z += __shfl_xor(z, off);
  } else {
    agg_node_big(hb, ss, sdn, base, deg, csr, lane, quarter, c16, lpw, acc, z);
  }
  acc.x += __shfl_xor(acc.x, 16);
  acc.y += __shfl_xor(acc.y, 16);
  acc.z += __shfl_xor(acc.z, 16);
  acc.w += __shfl_xor(acc.w, 16);
  acc.x += __shfl_xor(acc.x, 32);
  acc.y += __shfl_xor(acc.y, 32);
  acc.z += __shfl_xor(acc.z, 32);
  acc.w += __shfl_xor(acc.w, 32);
  float inv = 1.f / (z + 1e-16f);
  ox = acc.x * inv; oy = acc.y * inv;
  oz = acc.z * inv; ow = acc.w * inv;
  if (do_elu) {
    ox = (ox > 0.f) ? ox : expm1f(ox);
    oy = (oy > 0.f) ? oy : expm1f(oy);
    oz = (oz > 0.f) ? oz : expm1f(oz);
    ow = (ow > 0.f) ? ow : expm1f(ow);
  }
}

// ---------- fused agg->gemm (R12-measured best, 347.9/349.2us verified) ----------
__global__ __launch_bounds__(512) void k_fused(
    const unsigned short* __restrict__ hb_in, const float* __restrict__ ss_in,
    const float* __restrict__ sd_in, const int* __restrict__ rowp,
    const int* __restrict__ csr, const unsigned short* __restrict__ wfH,
    const unsigned short* __restrict__ wfL, const unsigned short* __restrict__ baf,
    int mat, int do_elu, unsigned short* __restrict__ hb_out,
    float* __restrict__ ss_out, float* __restrict__ sd_out) {
  __shared__ float outT[FROWS][FPAD];
  __shared__ __align__(16) int2 lps[8][4][64];  // per wave: 4 node buffers (16 KB)
  const int tid = threadIdx.x;
  const int lane = tid & 63;
  const int w = tid >> 6;  // 0..7
  const int quarter = lane >> 4;
  const int c16 = lane & 15;
  const int blk = blockIdx.x;
  const int node0 = blk * FROWS + w * 4;

  // wave-uniform row pointers (clamped: OOB nodes get deg 0)
  int bp[5];
#pragma unroll
  for (int j = 0; j < 5; ++j) {
    int idx = node0 + j;
    bp[j] = rowp[(idx < N_NODES) ? idx : N_NODES];
  }
  int deg[4];
  float sdn[4];
#pragma unroll
  for (int j = 0; j < 4; ++j) {
    deg[j] = bp[j + 1] - bp[j];
    int idx = node0 + j;
    sdn[j] = sd_in[(idx < N_NODES) ? idx : (N_NODES - 1)];
  }

  if (deg[0] <= 64 && deg[1] <= 64 && deg[2] <= 64 && deg[3] <= 64) {
    // ---- batched phase 1: 4 independent csr loads, then 4 independent ss gathers
    int s4[4];
    float p4[4];
#pragma unroll
    for (int j = 0; j < 4; ++j)
      s4[j] = (lane < deg[j]) ? csr[bp[j] + lane] : 0;
#pragma unroll
    for (int j = 0; j < 4; ++j) {
      float t = ss_in[s4[j]] + sdn[j];
      t = (t >= 0.f) ? t : 0.2f * t;
      p4[j] = (lane < deg[j]) ? __expf(t) : 0.f;
    }
#pragma unroll
    for (int j = 0; j < 4; ++j)
      lps[w][j][lane] = make_int2(__float_as_int(p4[j]), s4[j]);
    __builtin_amdgcn_wave_barrier();

    // ---- 4 gather loops (serial per node; compiler pipelines within each)
    float4 acc[4];
#pragma unroll
    for (int j = 0; j < 4; ++j) acc[j] = (float4){0.f, 0.f, 0.f, 0.f};
#pragma unroll
    for (int j = 0; j < 4; ++j)
      quad_accum(hb_in, &lps[w][j][0], deg[j], quarter, c16, acc[j]);

    // ---- z reductions + epilogues
#pragma unroll
    for (int j = 0; j < 4; ++j) {
      float z = p4[j];
#pragma unroll
      for (int off = 32; off > 0; off >>= 1) z += __shfl_xor(z, off);
      float4 a = acc[j];
      a.x += __shfl_xor(a.x, 16);
      a.y += __shfl_xor(a.y, 16);
      a.z += __shfl_xor(a.z, 16);
      a.w += __shfl_xor(a.w, 16);
      a.x += __shfl_xor(a.x, 32);
      a.y += __shfl_xor(a.y, 32);
      a.z += __shfl_xor(a.z, 32);
      a.w += __shfl_xor(a.w, 32);
      float inv = 1.f / (z + 1e-16f);
      float ox = a.x * inv, oy = a.y * inv, oz = a.z * inv, ow = a.w * inv;
      if (do_elu) {
        ox = (ox > 0.f) ? ox : expm1f(ox);
        oy = (oy > 0.f) ? oy : expm1f(oy);
        oz = (oz > 0.f) ? oz : expm1f(oz);
        ow = (ow > 0.f) ? ow : expm1f(ow);
      }
      if (quarter == 0) {
        float4 o4 = {ox, oy, oz, ow};
        *(float4*)&outT[w * 4 + j][4 * c16] = o4;  // 16B-aligned
      }
    }
  } else {
    // rare path: verified per-node serial agg
    for (int j = 0; j < 4; ++j) {
      const int row = w * 4 + j;
      const int node = node0 + j;
      float ox = 0.f, oy = 0.f, oz = 0.f, ow = 0.f;
      if (node < N_NODES)
        agg_core(hb_in, ss_in, sd_in, rowp, csr, node, lane, quarter, c16,
                 do_elu, &lps[w][j][0], ox, oy, oz, ow);
      if (quarter == 0) {
        float4 o4 = {ox, oy, oz, ow};
        *(float4*)&outT[row][4 * c16] = o4;
      }
    }
  }
  __syncthreads();

  // ---- gemm phase: wave w -> tile t=w>>2 (rows t*16..+15), cb=w&3 ----
  const int t = w >> 2;
  const int cb = w & 3;
  const int r16 = c16;
  const int g4 = quarter;

  bf16x8 Ah[2], Al[2];
#pragma unroll
  for (int ks = 0; ks < 2; ++ks) {
    const float* src = &outT[t * 16 + r16][32 * ks + 8 * g4];
    float4 f0 = *(const float4*)src;
    float4 f1 = *(const float4*)(src + 4);
    float v[8] = {f0.x, f0.y, f0.z, f0.w, f1.x, f1.y, f1.z, f1.w};
#pragma unroll
    for (int jj = 0; jj < 8; ++jj) {
      unsigned short hu = f2bf(v[jj]);
      Ah[ks][jj] = (short)hu;
      Al[ks][jj] = (short)f2bf(v[jj] - bf2f(hu));
    }
  }

  const bf16x8* WH = (const bf16x8*)wfH;
  const bf16x8* WL = (const bf16x8*)wfL;
  f32x4 acc2 = (f32x4){0.f, 0.f, 0.f, 0.f};
#pragma unroll
  for (int ks = 0; ks < 2; ++ks) {
    int fi = ((mat * 4 + cb) * 2 + ks) * 64 + lane;
    bf16x8 Bh = WH[fi];
    bf16x8 Bl = WL[fi];
    acc2 = __builtin_amdgcn_mfma_f32_16x16x32_bf16(Ah[ks], Bh, acc2, 0, 0, 0);
    acc2 = __builtin_amdgcn_mfma_f32_16x16x32_bf16(Al[ks], Bh, acc2, 0, 0, 0);
    acc2 = __builtin_amdgcn_mfma_f32_16x16x32_bf16(Ah[ks], Bl, acc2, 0, 0, 0);
  }
#pragma unroll
  for (int reg = 0; reg < 4; ++reg) {
    int row = blk * FROWS + t * 16 + 4 * g4 + reg;
    if (row < N_NODES) hb_out[row * DIM + cb * 16 + r16] = f2bf(acc2[reg]);
  }

  if (cb == 0) {
    f32x4 accs = (f32x4){0.f, 0.f, 0.f, 0.f};
#pragma unroll
    for (int ks = 0; ks < 2; ++ks) {
      bf16x8 Ba = *(const bf16x8*)(baf + ((mat * 2 + ks) * 64 + lane) * 8);
      accs = __builtin_amdgcn_mfma_f32_16x16x32_bf16(Ah[ks], Ba, accs, 0, 0, 0);
      accs = __builtin_amdgcn_mfma_f32_16x16x32_bf16(Al[ks], Ba, accs, 0, 0, 0);
    }
#pragma unroll
    for (int reg = 0; reg < 4; ++reg) {
      float tmp = accs[reg] + __shfl_xor(accs[reg], 1);  // col pairs
      int row = blk * FROWS + t * 16 + 4 * g4 + reg;
      if (row < N_NODES) {
        if (r16 == 0) ss_out[row] = tmp;
        else if (r16 == 2) sd_out[row] = tmp;
      }
    }
  }
}

// ---------- final-layer agg (R5-verified single-node; is_final path) ----------
__global__ __launch_bounds__(256) void k_agg(
    const unsigned short* __restrict__ hb, const float* __restrict__ ss,
    const float* __restrict__ sd, const int* __restrict__ rowp,
    const int* __restrict__ csr, void* __restrict__ out_final,
    const int* __restrict__ flags, int do_elu) {
  __shared__ __align__(16) int2 lps[4][64];
  const int lane = threadIdx.x & 63;
  const int quarter = lane >> 4;
  const int c16 = lane & 15;
  const int w = threadIdx.x >> 6;
  const int node = blockIdx.x * 4 + w;
  float ox, oy, oz, ow;
  agg_core(hb, ss, sd, rowp, csr, node, lane, quarter, c16, do_elu,
           &lps[w][0], ox, oy, oz, ow);
  if (quarter == 0) {
    int idx = node * DIM + 4 * c16;
    if (flags[0]) {
      ushort4 o4 = {f2bf(ox), f2bf(oy), f2bf(oz), f2bf(ow)};
      *(ushort4*)((unsigned short*)out_final + idx) = o4;
    } else {
      float4 o4 = {ox, oy, oz, ow};
      *(float4*)((float*)out_final + idx) = o4;
    }
  }
}

// ---------- launch ----------
extern "C" void kernel_launch(void* const* d_in, const int* in_sizes, int n_in,
                              void* d_out, int out_size, void* d_ws, size_t ws_size,
                              hipStream_t stream) {
  const void* feat = d_in[0];
  const int* eidx = (const int*)d_in[1];

  unsigned short* hbA = (unsigned short*)d_ws;          // N*64 bf16
  unsigned short* hbB = hbA + N_NODES * DIM;            // N*64 bf16
  unsigned short* wfH = hbB + N_NODES * DIM;            // 32768
  unsigned short* wfL = wfH + 32768;                    // 32768
  unsigned short* baf = wfL + 32768;                    // 8192
  int2* ebuf = (int2*)(baf + 8192);                     // E int2
  float* ssA = (float*)(ebuf + N_EDGES);                // N
  float* sdA = ssA + N_NODES;                           // N
  float* ssB = sdA + N_NODES;                           // N
  float* sdB = ssB + N_NODES;                           // N
  int* csr  = (int*)(sdB + N_NODES);                    // E
  int* hist = csr + N_EDGES;                            // NB*NBLK
  int* hscan = hist + NB * NBLK;                        // NB*NBLK
  int* bsum = hscan + NB * NBLK;                        // 256
  int* rowp = bsum + 256;                               // N+1
  int* flags = rowp + N_NODES + 1;                      // 2

  const int NH = NB * NBLK;                 // 50048
  const int SBH = (NH + 255) / 256;         // 196

  // R22: k_detect folded into k_wprep (block 0 publishes flags);
  //      k_scan2 folded into k_scan3 (per-block bsum reduce). 9 -> 7 dispatches.
  k_wprep<<<8, 256, 0, stream>>>(d_in[2], d_in[3], d_in[4],
                                 d_in[5], d_in[6], d_in[7],
                                 (const unsigned short*)feat,
                                 (const unsigned int*)eidx,
                                 flags, wfH, wfL, baf);
  k_hist1<<<NBLK, 256, 0, stream>>>(eidx, flags, hist);
  k_scan1<<<SBH, 256, 0, stream>>>(hist, hscan, bsum, NH);
  k_scan3<<<SBH, 256, 0, stream>>>(hscan, bsum, NH);
  k_scatter<<<NBLK, 256, 0, stream>>>(eidx, flags, hscan, ebuf);
  k_place<<<NB, 256, 0, stream>>>(ebuf, hscan, rowp, csr);

  const int GB = (2 * NTILES + 3) / 4;              // layer-0 gemm
  const int FB = (N_NODES + FROWS - 1) / FROWS;     // 1563 fused blocks

  // layer 0 gemm: features -> hbA, ssA, sdA (direct feat read)
  k_gemm<<<GB, 256, 0, stream>>>(feat, wfH, wfL, baf, 0, flags, hbA, ssA, sdA);

  // 7 fused layers: agg(k) + gemm(k+1). X_0 = A; alternate.
  for (int k = 0; k < 7; ++k) {
    const unsigned short* hin = (k & 1) ? hbB : hbA;
    const float* sin_ = (k & 1) ? ssB : ssA;
    const float* din = (k & 1) ? sdB : sdA;
    unsigned short* hout = (k & 1) ? hbA : hbB;
    float* sout = (k & 1) ? ssA : ssB;
    float* dout = (k & 1) ? sdA : sdB;
    k_fused<<<FB, 512, 0, stream>>>(hin, sin_, din, rowp, csr, wfH, wfL, baf,
                                    k + 1, (k == 3) ? 1 : 0, hout, sout, dout);
  }

  // final agg (layer 7): X_7 = B (7 fused flips from A)
  k_agg<<<N_NODES / 4, 256, 0, stream>>>(hbB, ssB, sdB, rowp, csr, d_out,
                                         flags, 1);
}